// Round 1
// baseline (6175.524 us; speedup 1.0000x reference)
//
#include <hip/hip_runtime.h>
#include <math.h>

#define N_U 30000
#define N_I 15000
#define N_TOT 45000
#define D 64
#define NNZ 480000
#define E_GAT 1005000
#define B 2048
#define INV_TEMP 5.0f
#define LOG_EPS -18.420680743952367f
#define NEG_SLOPE 0.2f
#define LAMBDA1 0.2f
#define LAMBDA2 1e-7f

__device__ inline float wred(float v) {
#pragma unroll
  for (int o = 32; o > 0; o >>= 1) v += __shfl_down(v, o, 64);
  return v;
}

__device__ inline void atomMaxF(float* a, float v) {
  if (v >= 0.f) atomicMax((int*)a, __float_as_int(v));
  else atomicMin((unsigned int*)a, __float_as_uint(v));
}

// ---------------- init: Eu/Ei/sums from E0, zero accumulators ----------------
__global__ void k_init(const float* __restrict__ Eu0, const float* __restrict__ Ei0,
                       float* Eu, float* Ei, float* sEu, float* sEi,
                       float* sGu, float* sGi, float* acc) {
  int t = blockIdx.x * 256 + threadIdx.x;
  if (t < 16) acc[t] = 0.f;
  if (t < N_U * D) {
    float v = Eu0[t]; Eu[t] = v; sEu[t] = v; sGu[t] = v;
  } else if (t < N_TOT * D) {
    int j = t - N_U * D;
    float v = Ei0[j]; Ei[j] = v; sEi[j] = v; sGi[j] = v;
  }
}

// ---------------- per-layer zero ----------------
__global__ void k_layer_zero(float* Z, float* gat, float* emax, float* denom) {
  int t = blockIdx.x * 256 + threadIdx.x;
  if (t < N_TOT * D) { Z[t] = 0.f; gat[t] = 0.f; }
  if (t < N_TOT * 4) { emax[t] = -INFINITY; denom[t] = 0.f; }
}

// ---------------- LightGCN scatter: Zu += v*Ei[i], Zi += v*Eu[u] ----------------
__global__ void k_lgcn(const float* __restrict__ Eu, const float* __restrict__ Ei,
                       const float* __restrict__ vals, const int* __restrict__ ui,
                       const int* __restrict__ ii, float* Zu, float* Zi) {
  int t = blockIdx.x * 256 + threadIdx.x;
  if (t >= NNZ * 16) return;
  int e = t >> 4, c = (t & 15) << 2;
  int u = ui[e], i = ii[e];
  float v = vals[e];
  float4 a = *(const float4*)(Ei + (size_t)i * D + c);
  float4 b = *(const float4*)(Eu + (size_t)u * D + c);
  float* zu = Zu + (size_t)u * D + c;
  float* zi = Zi + (size_t)i * D + c;
  unsafeAtomicAdd(zu + 0, v * a.x); unsafeAtomicAdd(zu + 1, v * a.y);
  unsafeAtomicAdd(zu + 2, v * a.z); unsafeAtomicAdd(zu + 3, v * a.w);
  unsafeAtomicAdd(zi + 0, v * b.x); unsafeAtomicAdd(zi + 1, v * b.y);
  unsafeAtomicAdd(zi + 2, v * b.z); unsafeAtomicAdd(zi + 3, v * b.w);
}

// ---------------- GAT: feat = h @ W, el/er head reductions ----------------
__global__ void k_feat(const float* __restrict__ Eu, const float* __restrict__ Ei,
                       const float* __restrict__ W, const float* __restrict__ al,
                       const float* __restrict__ ar,
                       float* __restrict__ feat, float* __restrict__ el, float* __restrict__ er) {
  __shared__ float Ws[64 * 64];
  __shared__ float hs[4][64];
  int tid = threadIdx.x;
#pragma unroll
  for (int t = tid; t < 4096; t += 256) Ws[t] = W[t];
  int nl = tid >> 6, c = tid & 63;
  int node = blockIdx.x * 4 + nl;
  if (node < N_TOT) {
    const float* src = (node < N_U) ? (Eu + (size_t)node * D) : (Ei + (size_t)(node - N_U) * D);
    hs[nl][c] = src[c];
  }
  __syncthreads();
  if (node < N_TOT) {
    float acc = 0.f;
#pragma unroll
    for (int k = 0; k < 64; ++k) acc = fmaf(hs[nl][k], Ws[k * 64 + c], acc);
    feat[(size_t)node * D + c] = acc;
    float pl = acc * al[c];
    float pr = acc * ar[c];
#pragma unroll
    for (int o = 8; o >= 1; o >>= 1) {
      pl += __shfl_down(pl, o, 16);
      pr += __shfl_down(pr, o, 16);
    }
    if ((c & 15) == 0) {
      el[node * 4 + (c >> 4)] = pl;
      er[node * 4 + (c >> 4)] = pr;
    }
  }
}

// ---------------- GAT edge pass 1: segment max ----------------
__global__ void k_edge_max(const int* __restrict__ src, const int* __restrict__ dst,
                           const float* __restrict__ el, const float* __restrict__ er,
                           float* emax) {
  int t = blockIdx.x * 256 + threadIdx.x;
  if (t >= E_GAT * 4) return;
  int e = t >> 2, h = t & 3;
  int s = src[e], d = dst[e];
  float v = el[s * 4 + h] + er[d * 4 + h];
  v = (v >= 0.f) ? v : NEG_SLOPE * v;
  atomMaxF(emax + d * 4 + h, v);
}

// ---------------- GAT edge pass 2: denom + unnormalized weighted aggregate ----------------
__global__ void k_edge_acc(const int* __restrict__ src, const int* __restrict__ dst,
                           const float* __restrict__ el, const float* __restrict__ er,
                           const float* __restrict__ emax, const float* __restrict__ feat,
                           float* denom, float* gat) {
  int t = blockIdx.x * 256 + threadIdx.x;
  if (t >= E_GAT * 16) return;
  int e = t >> 4, c = t & 15;
  int h = c >> 2;
  int s = src[e], d = dst[e];
  float v = el[s * 4 + h] + er[d * 4 + h];
  v = (v >= 0.f) ? v : NEG_SLOPE * v;
  float a = expf(v - emax[d * 4 + h]);
  if ((c & 3) == 0) unsafeAtomicAdd(denom + d * 4 + h, a);
  float4 f = *(const float4*)(feat + (size_t)s * D + c * 4);
  float* g = gat + (size_t)d * D + c * 4;
  unsafeAtomicAdd(g + 0, a * f.x); unsafeAtomicAdd(g + 1, a * f.y);
  unsafeAtomicAdd(g + 2, a * f.z); unsafeAtomicAdd(g + 3, a * f.w);
}

// ---------------- layer epilogue: normalize+elu (GAT), E update, running sums ----------------
__global__ void k_update(const float* __restrict__ Z, const float* __restrict__ gat,
                         const float* __restrict__ denom,
                         float* Eu, float* Ei, float* sEu, float* sEi,
                         float* sGu, float* sGi) {
  int t = blockIdx.x * 256 + threadIdx.x;
  if (t >= N_TOT * D) return;
  int n = t >> 6, c = t & 63;
  float o = gat[t] / denom[n * 4 + (c >> 4)];
  float g = (o > 0.f) ? o : expm1f(o);
  if (n < N_U) {
    float e = Eu[t] + Z[t];
    Eu[t] = e; sEu[t] += e; sGu[t] += g;
  } else {
    int j = t - N_U * D;
    float e = Ei[j] + Z[t];
    Ei[j] = e; sEi[j] += e; sGi[j] += g;
  }
}

// ---------------- tiled online logsumexp over G[ids[b]] . E[j] * invT ----------------
#define LQB 32
#define LTILE 128
#define LPAD 68

__global__ __launch_bounds__(256) void k_lse_part(
    const float* __restrict__ G, const int* __restrict__ ids,
    const float* __restrict__ E, int n_rows, int rows_per_split,
    float* part_m, float* part_s) {
  __shared__ float qs[LQB * LPAD];
  __shared__ float es[LTILE * LPAD];
  int tid = threadIdx.x;
  int qb = blockIdx.x, split = blockIdx.y, nsplit = gridDim.y;

  // load 32 query vectors (each 64 floats)
  for (int t = tid; t < LQB * 16; t += 256) {
    int q = t >> 4, c4 = (t & 15) << 2;
    int b = qb * LQB + q;
    float4 v = *(const float4*)(G + (size_t)ids[b] * D + c4);
    float* p = qs + q * LPAD + c4;
    p[0] = v.x; p[1] = v.y; p[2] = v.z; p[3] = v.w;
  }

  int row0 = split * rows_per_split;
  int row_end = min(row0 + rows_per_split, n_rows);
  int qq = tid & 7, jg = tid >> 3;  // qq: query group (queries qq+8*qi), jg: row lane (rows jg+32*jj)
  float m0 = -INFINITY, m1 = -INFINITY, m2 = -INFINITY, m3 = -INFINITY;
  float s0 = 0.f, s1 = 0.f, s2 = 0.f, s3 = 0.f;

  for (int base = row0; base < row_end; base += LTILE) {
    __syncthreads();
    int nvalid = row_end - base;
    for (int t = tid; t < LTILE * 16; t += 256) {
      int r = t >> 4, c4 = (t & 15) << 2;
      float4 v = (r < nvalid) ? *(const float4*)(E + (size_t)(base + r) * D + c4)
                              : make_float4(0.f, 0.f, 0.f, 0.f);
      float* p = es + r * LPAD + c4;
      p[0] = v.x; p[1] = v.y; p[2] = v.z; p[3] = v.w;
    }
    __syncthreads();

    float dot[4][4];
#pragma unroll
    for (int a = 0; a < 4; a++)
#pragma unroll
      for (int b2 = 0; b2 < 4; b2++) dot[a][b2] = 0.f;

#pragma unroll
    for (int k = 0; k < 64; k += 4) {
      float4 qv[4], ev[4];
#pragma unroll
      for (int qi = 0; qi < 4; qi++) qv[qi] = *(const float4*)(qs + (qq + 8 * qi) * LPAD + k);
#pragma unroll
      for (int jj = 0; jj < 4; jj++) ev[jj] = *(const float4*)(es + (jg + 32 * jj) * LPAD + k);
#pragma unroll
      for (int qi = 0; qi < 4; qi++)
#pragma unroll
        for (int jj = 0; jj < 4; jj++) {
          dot[qi][jj] = fmaf(qv[qi].x, ev[jj].x, dot[qi][jj]);
          dot[qi][jj] = fmaf(qv[qi].y, ev[jj].y, dot[qi][jj]);
          dot[qi][jj] = fmaf(qv[qi].z, ev[jj].z, dot[qi][jj]);
          dot[qi][jj] = fmaf(qv[qi].w, ev[jj].w, dot[qi][jj]);
        }
    }

#pragma unroll
    for (int jj = 0; jj < 4; jj++) {
      if (jg + 32 * jj < nvalid) {
        float d;
        d = dot[0][jj] * INV_TEMP; if (d > m0) { s0 = s0 * expf(m0 - d) + 1.f; m0 = d; } else s0 += expf(d - m0);
        d = dot[1][jj] * INV_TEMP; if (d > m1) { s1 = s1 * expf(m1 - d) + 1.f; m1 = d; } else s1 += expf(d - m1);
        d = dot[2][jj] * INV_TEMP; if (d > m2) { s2 = s2 * expf(m2 - d) + 1.f; m2 = d; } else s2 += expf(d - m2);
        d = dot[3][jj] * INV_TEMP; if (d > m3) { s3 = s3 * expf(m3 - d) + 1.f; m3 = d; } else s3 += expf(d - m3);
      }
    }
  }

  // combine across the 32 jg threads per query
  __syncthreads();
  float* rm = es;          // 1024 floats
  float* rs = es + 1024;   // 1024 floats
  rm[(qq + 0) * 32 + jg] = m0;  rs[(qq + 0) * 32 + jg] = s0;
  rm[(qq + 8) * 32 + jg] = m1;  rs[(qq + 8) * 32 + jg] = s1;
  rm[(qq + 16) * 32 + jg] = m2; rs[(qq + 16) * 32 + jg] = s2;
  rm[(qq + 24) * 32 + jg] = m3; rs[(qq + 24) * 32 + jg] = s3;
  __syncthreads();
  if (tid < 32) {
    float mm = -INFINITY, ss = 0.f;
    for (int j = 0; j < 32; j++) {
      float mj = rm[tid * 32 + j];
      if (mj == -INFINITY) continue;
      float sj = rs[tid * 32 + j];
      if (mj > mm) { ss = ss * expf(mm - mj) + sj; mm = mj; }
      else ss += sj * expf(mj - mm);
    }
    int b = qb * LQB + tid;
    part_m[(size_t)b * nsplit + split] = mm;
    part_s[(size_t)b * nsplit + split] = ss;
  }
}

// ---------------- L2 regularization reduce ----------------
__global__ void k_reg(const float* __restrict__ Eu0, const float* __restrict__ Ei0, float* acc) {
  int t = blockIdx.x * 256 + threadIdx.x;
  float v = 0.f;
  if (t < N_U * D) v = Eu0[t];
  else if (t < N_TOT * D) v = Ei0[t - N_U * D];
  float sq = wred(v * v);
  if ((threadIdx.x & 63) == 0) unsafeAtomicAdd(acc + 5, sq);
}

// ---------------- per-sample losses: lse combine, pos dots, BPR ----------------
__global__ void k_small(const float* __restrict__ sEu, const float* __restrict__ sEi,
                        const float* __restrict__ sGu, const float* __restrict__ sGi,
                        const int* __restrict__ uids, const int* __restrict__ iids,
                        const int* __restrict__ pos, const int* __restrict__ neg,
                        const float* __restrict__ pmU, const float* __restrict__ psU,
                        const float* __restrict__ pmI, const float* __restrict__ psI,
                        float* acc) {
  int b = blockIdx.x * 256 + threadIdx.x;
  float du = 0.f, di = 0.f, nu = 0.f, ni = 0.f, bpr = 0.f;
  if (b < B) {
    float mm = -INFINITY, ss = 0.f;
    for (int s2 = 0; s2 < 8; s2++) {
      float mj = pmU[b * 8 + s2];
      if (mj == -INFINITY) continue;
      float sj = psU[b * 8 + s2];
      if (mj > mm) { ss = ss * expf(mm - mj) + sj; mm = mj; } else ss += sj * expf(mj - mm);
    }
    float lseu = mm + logf(ss);
    mm = -INFINITY; ss = 0.f;
    for (int s2 = 0; s2 < 4; s2++) {
      float mj = pmI[b * 4 + s2];
      if (mj == -INFINITY) continue;
      float sj = psI[b * 4 + s2];
      if (mj > mm) { ss = ss * expf(mm - mj) + sj; mm = mj; } else ss += sj * expf(mj - mm);
    }
    float lsei = mm + logf(ss);
    nu = fmaxf(lseu, LOG_EPS) + log1pf(expf(-fabsf(lseu - LOG_EPS)));
    ni = fmaxf(lsei, LOG_EPS) + log1pf(expf(-fabsf(lsei - LOG_EPS)));

    int u = uids[b], it = iids[b], p = pos[b], ng = neg[b];
    const float4* gu = (const float4*)(sGu + (size_t)u * D);
    const float4* eu = (const float4*)(sEu + (size_t)u * D);
    const float4* gi = (const float4*)(sGi + (size_t)it * D);
    const float4* ei = (const float4*)(sEi + (size_t)it * D);
    const float4* ep = (const float4*)(sEi + (size_t)p * D);
    const float4* en = (const float4*)(sEi + (size_t)ng * D);
    float diff = 0.f;
#pragma unroll
    for (int k = 0; k < 16; k++) {
      float4 a = gu[k], b4 = eu[k];
      du += a.x * b4.x + a.y * b4.y + a.z * b4.z + a.w * b4.w;
      float4 c = gi[k], d4 = ei[k];
      di += c.x * d4.x + c.y * d4.y + c.z * d4.z + c.w * d4.w;
      float4 e = ep[k], f = en[k];
      diff += b4.x * (e.x - f.x) + b4.y * (e.y - f.y) + b4.z * (e.z - f.z) + b4.w * (e.w - f.w);
    }
    bpr = (diff > 0.f) ? log1pf(expf(-diff)) : (-diff + log1pf(expf(diff)));
  }
  du = wred(du); di = wred(di); nu = wred(nu); ni = wred(ni); bpr = wred(bpr);
  if ((threadIdx.x & 63) == 0) {
    unsafeAtomicAdd(acc + 0, du);
    unsafeAtomicAdd(acc + 1, di);
    unsafeAtomicAdd(acc + 2, nu);
    unsafeAtomicAdd(acc + 3, ni);
    unsafeAtomicAdd(acc + 4, bpr);
  }
}

// ---------------- finalize ----------------
__global__ void k_final(const float* __restrict__ acc, float* __restrict__ out) {
  float pos_score = (acc[0] + acc[1]) * (INV_TEMP / (float)B);
  float neg_score = (acc[2] + acc[3]) / (float)B;
  float loss_s = neg_score - pos_score;
  float loss_r = acc[4] / (float)B;
  float reg = LAMBDA2 * acc[5];
  out[0] = loss_r + LAMBDA1 * loss_s + reg;
  out[1] = loss_r;
  out[2] = LAMBDA1 * loss_s;
}

extern "C" void kernel_launch(void* const* d_in, const int* in_sizes, int n_in,
                              void* d_out, int out_size, void* d_ws, size_t ws_size,
                              hipStream_t stream) {
  const float* Eu0  = (const float*)d_in[0];
  const float* Ei0  = (const float*)d_in[1];
  const float* vals = (const float*)d_in[2];
  const float* W    = (const float*)d_in[3];
  const float* al   = (const float*)d_in[4];
  const float* ar   = (const float*)d_in[5];
  const int* ui     = (const int*)d_in[6];
  const int* ii     = (const int*)d_in[7];
  const int* src    = (const int*)d_in[8];
  const int* dst    = (const int*)d_in[9];
  const int* uids   = (const int*)d_in[10];
  const int* iids   = (const int*)d_in[11];
  const int* pos    = (const int*)d_in[12];
  const int* neg    = (const int*)d_in[13];
  float* out = (float*)d_out;

  float* w = (float*)d_ws;
  size_t off = 0;
  float* Eu   = w + off; off += (size_t)N_U * D;
  float* Ei   = w + off; off += (size_t)N_I * D;
  float* sEu  = w + off; off += (size_t)N_U * D;
  float* sEi  = w + off; off += (size_t)N_I * D;
  float* sGu  = w + off; off += (size_t)N_U * D;
  float* sGi  = w + off; off += (size_t)N_I * D;
  float* Z    = w + off; off += (size_t)N_TOT * D;   // Zu = Z, Zi = Z + N_U*D
  float* feat = w + off; off += (size_t)N_TOT * D;
  float* gat  = w + off; off += (size_t)N_TOT * D;
  float* el   = w + off; off += (size_t)N_TOT * 4;
  float* er   = w + off; off += (size_t)N_TOT * 4;
  float* emax = w + off; off += (size_t)N_TOT * 4;
  float* denom= w + off; off += (size_t)N_TOT * 4;
  float* pmU  = w + off; off += (size_t)B * 8;
  float* psU  = w + off; off += (size_t)B * 8;
  float* pmI  = w + off; off += (size_t)B * 4;
  float* psI  = w + off; off += (size_t)B * 4;
  float* acc  = w + off; off += 16;

  k_init<<<(N_TOT * D + 255) / 256, 256, 0, stream>>>(Eu0, Ei0, Eu, Ei, sEu, sEi, sGu, sGi, acc);

  for (int l = 0; l < 2; ++l) {
    k_layer_zero<<<(N_TOT * D + 255) / 256, 256, 0, stream>>>(Z, gat, emax, denom);
    k_lgcn<<<(NNZ * 16) / 256, 256, 0, stream>>>(Eu, Ei, vals, ui, ii, Z, Z + (size_t)N_U * D);
    k_feat<<<N_TOT / 4, 256, 0, stream>>>(Eu, Ei, W, al, ar, feat, el, er);
    k_edge_max<<<(E_GAT * 4 + 255) / 256, 256, 0, stream>>>(src, dst, el, er, emax);
    k_edge_acc<<<(E_GAT * 16 + 255) / 256, 256, 0, stream>>>(src, dst, el, er, emax, feat, denom, gat);
    k_update<<<(N_TOT * D + 255) / 256, 256, 0, stream>>>(Z, gat, denom, Eu, Ei, sEu, sEi, sGu, sGi);
  }

  k_lse_part<<<dim3(B / LQB, 8), 256, 0, stream>>>(sGu, uids, sEu, N_U, 3750, pmU, psU);
  k_lse_part<<<dim3(B / LQB, 4), 256, 0, stream>>>(sGi, iids, sEi, N_I, 3750, pmI, psI);
  k_reg<<<(N_TOT * D + 255) / 256, 256, 0, stream>>>(Eu0, Ei0, acc);
  k_small<<<B / 256, 256, 0, stream>>>(sEu, sEi, sGu, sGi, uids, iids, pos, neg,
                                       pmU, psU, pmI, psI, acc);
  k_final<<<1, 1, 0, stream>>>(acc, out);
}

// Round 2
// 1509.279 us; speedup vs baseline: 4.0917x; 4.0917x over previous
//
#include <hip/hip_runtime.h>
#include <math.h>

#define N_U 30000
#define N_I 15000
#define N_TOT 45000
#define D 64
#define NNZ 480000
#define B 2048
#define INV_TEMP 5.0f
#define LOG_EPS -18.420680743952367f
#define NEG_SLOPE 0.2f
#define LAMBDA1 0.2f
#define LAMBDA2 1e-7f
#define NSPU 12
#define NSPI 6
#define ROWS_PER_SPLIT 2500

__device__ inline float wred(float v) {
#pragma unroll
  for (int o = 32; o > 0; o >>= 1) v += __shfl_down(v, o, 64);
  return v;
}

__device__ inline float leaky(float v) { return (v >= 0.f) ? v : NEG_SLOPE * v; }

// ---------------- init: Eu/Ei/sums from E0, zero deg + acc ----------------
__global__ void k_init(const float* __restrict__ Eu0, const float* __restrict__ Ei0,
                       float* Eu, float* Ei, float* sEu, float* sEi,
                       float* sGu, float* sGi, int* deg, float* acc) {
  int t = blockIdx.x * 256 + threadIdx.x;
  if (t < 16) acc[t] = 0.f;
  if (t < N_I) deg[t] = 0;
  if (t < N_U * D) {
    float v = Eu0[t]; Eu[t] = v; sEu[t] = v; sGu[t] = v;
  } else if (t < N_TOT * D) {
    int j = t - N_U * D;
    float v = Ei0[j]; Ei[j] = v; sEi[j] = v; sGi[j] = v;
  }
}

// ---------------- CSR build over item side ----------------
__global__ void k_deg(const int* __restrict__ ii, int* deg) {
  int e = blockIdx.x * 256 + threadIdx.x;
  if (e < NNZ) atomicAdd(&deg[ii[e]], 1);
}

__global__ void k_scan(const int* __restrict__ deg, int* rowptr, int* cursor) {
  __shared__ int buf[256];
  __shared__ int carry;
  int tid = threadIdx.x;
  if (tid == 0) carry = 0;
  __syncthreads();
  for (int base = 0; base < N_I; base += 256) {
    int v = (base + tid < N_I) ? deg[base + tid] : 0;
    buf[tid] = v;
    __syncthreads();
    for (int o = 1; o < 256; o <<= 1) {
      int x = (tid >= o) ? buf[tid - o] : 0;
      __syncthreads();
      buf[tid] += x;
      __syncthreads();
    }
    if (base + tid < N_I) {
      int excl = carry + buf[tid] - v;
      rowptr[base + tid] = excl;
      cursor[base + tid] = excl;
    }
    __syncthreads();
    if (tid == 255) carry += buf[255];
    __syncthreads();
  }
  if (tid == 0) rowptr[N_I] = carry;
}

__global__ void k_fill(const int* __restrict__ ii, int* cursor, int* eids) {
  int e = blockIdx.x * 256 + threadIdx.x;
  if (e < NNZ) {
    int pos = atomicAdd(&cursor[ii[e]], 1);
    eids[pos] = e;
  }
}

// ---------------- GAT: feat = h @ W, el/er head reductions ----------------
// 16 nodes per block (W tile amortized 4x better than 4/block)
__global__ void k_feat(const float* __restrict__ Eu, const float* __restrict__ Ei,
                       const float* __restrict__ W, const float* __restrict__ al,
                       const float* __restrict__ ar,
                       float* __restrict__ feat, float* __restrict__ el, float* __restrict__ er) {
  __shared__ float Ws[64 * 64];
  __shared__ float hs[16][64];
  int tid = threadIdx.x;
  for (int t = tid; t < 1024; t += 256) ((float4*)Ws)[t] = ((const float4*)W)[t];
  int g = tid >> 6, c = tid & 63;
  int n0 = blockIdx.x * 16 + g * 4;
#pragma unroll
  for (int j = 0; j < 4; j++) {
    int node = n0 + j;
    if (node < N_TOT) {
      const float* src = (node < N_U) ? (Eu + (size_t)node * D) : (Ei + (size_t)(node - N_U) * D);
      hs[g * 4 + j][c] = src[c];
    }
  }
  __syncthreads();
  float a0 = 0.f, a1 = 0.f, a2 = 0.f, a3 = 0.f;
#pragma unroll 8
  for (int k = 0; k < 64; ++k) {
    float w = Ws[k * 64 + c];
    a0 = fmaf(hs[g * 4 + 0][k], w, a0);
    a1 = fmaf(hs[g * 4 + 1][k], w, a1);
    a2 = fmaf(hs[g * 4 + 2][k], w, a2);
    a3 = fmaf(hs[g * 4 + 3][k], w, a3);
  }
  float accs[4] = {a0, a1, a2, a3};
  float alc = al[c], arc = ar[c];
#pragma unroll
  for (int j = 0; j < 4; j++) {
    int node = n0 + j;
    if (node >= N_TOT) continue;
    feat[(size_t)node * D + c] = accs[j];
    float pl = accs[j] * alc;
    float pr = accs[j] * arc;
#pragma unroll
    for (int o = 8; o >= 1; o >>= 1) {
      pl += __shfl_down(pl, o, 16);
      pr += __shfl_down(pr, o, 16);
    }
    if ((c & 15) == 0) {
      el[node * 4 + (c >> 4)] = pl;
      er[node * 4 + (c >> 4)] = pr;
    }
  }
}

// ---------------- fused user-side layer: LightGCN gather + GAT softmax-agg + update ----------------
// one 64-lane wave per user; lane = feature dim; no atomics
__global__ void k_user_layer(const float* __restrict__ curEu, const float* __restrict__ curEi,
                             const float* __restrict__ feat, const float* __restrict__ el,
                             const float* __restrict__ er, const float* __restrict__ vals,
                             const int* __restrict__ ii,
                             float* __restrict__ nxtEu, float* __restrict__ sEu,
                             float* __restrict__ sGu) {
  int t = blockIdx.x * 256 + threadIdx.x;
  int u = t >> 6, c = t & 63;
  if (u >= N_U) return;
  int h = c >> 4;
  float eru = er[u * 4 + h];
  float lself = leaky(el[u * 4 + h] + eru);
  float m = lself;
  float z = 0.f;
  int idx[16];
  float lv[16];
#pragma unroll
  for (int k = 0; k < 16; k++) {
    int e = u * 16 + k;
    int i = ii[e];
    idx[k] = i;
    z = fmaf(vals[e], curEi[(size_t)i * D + c], z);
    float l = leaky(el[(i + N_U) * 4 + h] + eru);
    lv[k] = l;
    m = fmaxf(m, l);
  }
  float aself = __expf(lself - m);
  float denom = aself;
  float o = aself * feat[(size_t)u * D + c];
#pragma unroll
  for (int k = 0; k < 16; k++) {
    float a = __expf(lv[k] - m);
    denom += a;
    o = fmaf(a, feat[(size_t)(idx[k] + N_U) * D + c], o);
  }
  o /= denom;
  float g = (o > 0.f) ? o : expm1f(o);
  size_t off = (size_t)u * D + c;
  float e_new = curEu[off] + z;
  nxtEu[off] = e_new;
  sEu[off] += e_new;
  sGu[off] += g;
}

// ---------------- fused item-side layer (CSR gather, variable degree) ----------------
__global__ void k_item_layer(const float* __restrict__ curEu, const float* __restrict__ curEi,
                             const float* __restrict__ feat, const float* __restrict__ el,
                             const float* __restrict__ er, const float* __restrict__ vals,
                             const int* __restrict__ ui, const int* __restrict__ rowptr,
                             const int* __restrict__ eids,
                             float* __restrict__ nxtEi, float* __restrict__ sEi,
                             float* __restrict__ sGi) {
  int t = blockIdx.x * 256 + threadIdx.x;
  int i = t >> 6, c = t & 63;
  if (i >= N_I) return;
  int h = c >> 4;
  int node = N_U + i;
  float eri = er[node * 4 + h];
  float lself = leaky(el[node * 4 + h] + eri);
  float m = lself;
  float z = 0.f;
  int r0 = rowptr[i], r1 = rowptr[i + 1];
  for (int r = r0; r < r1; r++) {
    int e = eids[r];
    int u = ui[e];
    z = fmaf(vals[e], curEu[(size_t)u * D + c], z);
    float l = leaky(el[u * 4 + h] + eri);
    m = fmaxf(m, l);
  }
  float aself = __expf(lself - m);
  float denom = aself;
  float o = aself * feat[(size_t)node * D + c];
  for (int r = r0; r < r1; r++) {
    int e = eids[r];
    int u = ui[e];
    float a = __expf(leaky(el[u * 4 + h] + eri) - m);
    denom += a;
    o = fmaf(a, feat[(size_t)u * D + c], o);
  }
  o /= denom;
  float g = (o > 0.f) ? o : expm1f(o);
  size_t off = (size_t)i * D + c;
  float e_new = curEi[off] + z;
  nxtEi[off] = e_new;
  sEi[off] += e_new;
  sGi[off] += g;
}

// ---------------- tiled online logsumexp over G[ids[b]] . E[j] * invT ----------------
#define LQB 32
#define LTILE 128
#define LPAD 68

__global__ __launch_bounds__(256, 3) void k_lse_part(
    const float* __restrict__ G, const int* __restrict__ ids,
    const float* __restrict__ E, int n_rows,
    float* part_m, float* part_s) {
  __shared__ float qs[LQB * LPAD];
  __shared__ float es[LTILE * LPAD];
  int tid = threadIdx.x;
  int qb = blockIdx.x, split = blockIdx.y, nsplit = gridDim.y;

  for (int t = tid; t < LQB * 16; t += 256) {
    int q = t >> 4, c4 = (t & 15) << 2;
    int b = qb * LQB + q;
    float4 v = *(const float4*)(G + (size_t)ids[b] * D + c4);
    float* p = qs + q * LPAD + c4;
    p[0] = v.x; p[1] = v.y; p[2] = v.z; p[3] = v.w;
  }

  int row0 = split * ROWS_PER_SPLIT;
  int row_end = min(row0 + ROWS_PER_SPLIT, n_rows);
  int qq = tid & 7, jg = tid >> 3;
  float m0 = -INFINITY, m1 = -INFINITY, m2 = -INFINITY, m3 = -INFINITY;
  float s0 = 0.f, s1 = 0.f, s2 = 0.f, s3 = 0.f;

  const float* q0 = qs + (qq + 0) * LPAD;
  const float* q1 = qs + (qq + 8) * LPAD;
  const float* q2 = qs + (qq + 16) * LPAD;
  const float* q3 = qs + (qq + 24) * LPAD;

  for (int base = row0; base < row_end; base += LTILE) {
    __syncthreads();
    int nvalid = row_end - base;
    for (int t = tid; t < LTILE * 16; t += 256) {
      int r = t >> 4, c4 = (t & 15) << 2;
      float4 v = (r < nvalid) ? *(const float4*)(E + (size_t)(base + r) * D + c4)
                              : make_float4(0.f, 0.f, 0.f, 0.f);
      float* p = es + r * LPAD + c4;
      p[0] = v.x; p[1] = v.y; p[2] = v.z; p[3] = v.w;
    }
    __syncthreads();

    float dot[4][4];
#pragma unroll
    for (int a = 0; a < 4; a++)
#pragma unroll
      for (int b2 = 0; b2 < 4; b2++) dot[a][b2] = 0.f;

#pragma unroll 4
    for (int k = 0; k < 64; k += 4) {
      float4 qv[4], ev[4];
      qv[0] = *(const float4*)(q0 + k);
      qv[1] = *(const float4*)(q1 + k);
      qv[2] = *(const float4*)(q2 + k);
      qv[3] = *(const float4*)(q3 + k);
#pragma unroll
      for (int jj = 0; jj < 4; jj++) ev[jj] = *(const float4*)(es + (jg + 32 * jj) * LPAD + k);
#pragma unroll
      for (int qi = 0; qi < 4; qi++)
#pragma unroll
        for (int jj = 0; jj < 4; jj++) {
          dot[qi][jj] = fmaf(qv[qi].x, ev[jj].x, dot[qi][jj]);
          dot[qi][jj] = fmaf(qv[qi].y, ev[jj].y, dot[qi][jj]);
          dot[qi][jj] = fmaf(qv[qi].z, ev[jj].z, dot[qi][jj]);
          dot[qi][jj] = fmaf(qv[qi].w, ev[jj].w, dot[qi][jj]);
        }
    }

#pragma unroll
    for (int jj = 0; jj < 4; jj++) {
      if (jg + 32 * jj < nvalid) {
        float d;
        d = dot[0][jj] * INV_TEMP; if (d > m0) { s0 = s0 * __expf(m0 - d) + 1.f; m0 = d; } else s0 += __expf(d - m0);
        d = dot[1][jj] * INV_TEMP; if (d > m1) { s1 = s1 * __expf(m1 - d) + 1.f; m1 = d; } else s1 += __expf(d - m1);
        d = dot[2][jj] * INV_TEMP; if (d > m2) { s2 = s2 * __expf(m2 - d) + 1.f; m2 = d; } else s2 += __expf(d - m2);
        d = dot[3][jj] * INV_TEMP; if (d > m3) { s3 = s3 * __expf(m3 - d) + 1.f; m3 = d; } else s3 += __expf(d - m3);
      }
    }
  }

  __syncthreads();
  float* rm = es;
  float* rs = es + 1024;
  rm[(qq + 0) * 32 + jg] = m0;  rs[(qq + 0) * 32 + jg] = s0;
  rm[(qq + 8) * 32 + jg] = m1;  rs[(qq + 8) * 32 + jg] = s1;
  rm[(qq + 16) * 32 + jg] = m2; rs[(qq + 16) * 32 + jg] = s2;
  rm[(qq + 24) * 32 + jg] = m3; rs[(qq + 24) * 32 + jg] = s3;
  __syncthreads();
  if (tid < 32) {
    float mm = -INFINITY, ss = 0.f;
    for (int j = 0; j < 32; j++) {
      float mj = rm[tid * 32 + j];
      if (mj == -INFINITY) continue;
      float sj = rs[tid * 32 + j];
      if (mj > mm) { ss = ss * __expf(mm - mj) + sj; mm = mj; }
      else ss += sj * __expf(mj - mm);
    }
    int b = qb * LQB + tid;
    part_m[(size_t)b * nsplit + split] = mm;
    part_s[(size_t)b * nsplit + split] = ss;
  }
}

// ---------------- L2 regularization reduce ----------------
__global__ void k_reg(const float* __restrict__ Eu0, const float* __restrict__ Ei0, float* acc) {
  int t = blockIdx.x * 256 + threadIdx.x;
  float v = 0.f;
  if (t < N_U * D) v = Eu0[t];
  else if (t < N_TOT * D) v = Ei0[t - N_U * D];
  float sq = wred(v * v);
  if ((threadIdx.x & 63) == 0) unsafeAtomicAdd(acc + 5, sq);
}

// ---------------- per-sample losses: lse combine, pos dots, BPR ----------------
__global__ void k_small(const float* __restrict__ sEu, const float* __restrict__ sEi,
                        const float* __restrict__ sGu, const float* __restrict__ sGi,
                        const int* __restrict__ uids, const int* __restrict__ iids,
                        const int* __restrict__ pos, const int* __restrict__ neg,
                        const float* __restrict__ pmU, const float* __restrict__ psU,
                        const float* __restrict__ pmI, const float* __restrict__ psI,
                        float* acc) {
  int b = blockIdx.x * 256 + threadIdx.x;
  float du = 0.f, di = 0.f, nu = 0.f, ni = 0.f, bpr = 0.f;
  if (b < B) {
    float mm = -INFINITY, ss = 0.f;
    for (int s2 = 0; s2 < NSPU; s2++) {
      float mj = pmU[b * NSPU + s2];
      if (mj == -INFINITY) continue;
      float sj = psU[b * NSPU + s2];
      if (mj > mm) { ss = ss * __expf(mm - mj) + sj; mm = mj; } else ss += sj * __expf(mj - mm);
    }
    float lseu = mm + logf(ss);
    mm = -INFINITY; ss = 0.f;
    for (int s2 = 0; s2 < NSPI; s2++) {
      float mj = pmI[b * NSPI + s2];
      if (mj == -INFINITY) continue;
      float sj = psI[b * NSPI + s2];
      if (mj > mm) { ss = ss * __expf(mm - mj) + sj; mm = mj; } else ss += sj * __expf(mj - mm);
    }
    float lsei = mm + logf(ss);
    nu = fmaxf(lseu, LOG_EPS) + log1pf(expf(-fabsf(lseu - LOG_EPS)));
    ni = fmaxf(lsei, LOG_EPS) + log1pf(expf(-fabsf(lsei - LOG_EPS)));

    int u = uids[b], it = iids[b], p = pos[b], ng = neg[b];
    const float4* gu = (const float4*)(sGu + (size_t)u * D);
    const float4* eu = (const float4*)(sEu + (size_t)u * D);
    const float4* gi = (const float4*)(sGi + (size_t)it * D);
    const float4* ei = (const float4*)(sEi + (size_t)it * D);
    const float4* ep = (const float4*)(sEi + (size_t)p * D);
    const float4* en = (const float4*)(sEi + (size_t)ng * D);
    float diff = 0.f;
#pragma unroll
    for (int k = 0; k < 16; k++) {
      float4 a = gu[k], b4 = eu[k];
      du += a.x * b4.x + a.y * b4.y + a.z * b4.z + a.w * b4.w;
      float4 c = gi[k], d4 = ei[k];
      di += c.x * d4.x + c.y * d4.y + c.z * d4.z + c.w * d4.w;
      float4 e = ep[k], f = en[k];
      diff += b4.x * (e.x - f.x) + b4.y * (e.y - f.y) + b4.z * (e.z - f.z) + b4.w * (e.w - f.w);
    }
    bpr = (diff > 0.f) ? log1pf(expf(-diff)) : (-diff + log1pf(expf(diff)));
  }
  du = wred(du); di = wred(di); nu = wred(nu); ni = wred(ni); bpr = wred(bpr);
  if ((threadIdx.x & 63) == 0) {
    unsafeAtomicAdd(acc + 0, du);
    unsafeAtomicAdd(acc + 1, di);
    unsafeAtomicAdd(acc + 2, nu);
    unsafeAtomicAdd(acc + 3, ni);
    unsafeAtomicAdd(acc + 4, bpr);
  }
}

// ---------------- finalize ----------------
__global__ void k_final(const float* __restrict__ acc, float* __restrict__ out) {
  float pos_score = (acc[0] + acc[1]) * (INV_TEMP / (float)B);
  float neg_score = (acc[2] + acc[3]) / (float)B;
  float loss_s = neg_score - pos_score;
  float loss_r = acc[4] / (float)B;
  float reg = LAMBDA2 * acc[5];
  out[0] = loss_r + LAMBDA1 * loss_s + reg;
  out[1] = loss_r;
  out[2] = LAMBDA1 * loss_s;
}

extern "C" void kernel_launch(void* const* d_in, const int* in_sizes, int n_in,
                              void* d_out, int out_size, void* d_ws, size_t ws_size,
                              hipStream_t stream) {
  const float* Eu0  = (const float*)d_in[0];
  const float* Ei0  = (const float*)d_in[1];
  const float* vals = (const float*)d_in[2];
  const float* W    = (const float*)d_in[3];
  const float* al   = (const float*)d_in[4];
  const float* ar   = (const float*)d_in[5];
  const int* ui     = (const int*)d_in[6];
  const int* ii     = (const int*)d_in[7];
  const int* uids   = (const int*)d_in[10];
  const int* iids   = (const int*)d_in[11];
  const int* pos    = (const int*)d_in[12];
  const int* neg    = (const int*)d_in[13];
  float* out = (float*)d_out;

  float* w = (float*)d_ws;
  size_t off = 0;
  float* Eu_a = w + off; off += (size_t)N_U * D;
  float* Ei_a = w + off; off += (size_t)N_I * D;
  float* Eu_b = w + off; off += (size_t)N_U * D;
  float* Ei_b = w + off; off += (size_t)N_I * D;
  float* sEu  = w + off; off += (size_t)N_U * D;
  float* sEi  = w + off; off += (size_t)N_I * D;
  float* sGu  = w + off; off += (size_t)N_U * D;
  float* sGi  = w + off; off += (size_t)N_I * D;
  float* feat = w + off; off += (size_t)N_TOT * D;
  float* el   = w + off; off += (size_t)N_TOT * 4;
  float* er   = w + off; off += (size_t)N_TOT * 4;
  float* pmU  = w + off; off += (size_t)B * NSPU;
  float* psU  = w + off; off += (size_t)B * NSPU;
  float* pmI  = w + off; off += (size_t)B * NSPI;
  float* psI  = w + off; off += (size_t)B * NSPI;
  float* acc  = w + off; off += 16;
  int* iw = (int*)(w + off);
  int* deg    = iw;                 // N_I
  int* cursor = iw + N_I;           // N_I
  int* rowptr = iw + 2 * N_I;       // N_I + 1
  int* eids   = iw + 3 * N_I + 1;   // NNZ

  k_init<<<(N_TOT * D + 255) / 256, 256, 0, stream>>>(Eu0, Ei0, Eu_a, Ei_a, sEu, sEi, sGu, sGi, deg, acc);
  k_deg<<<(NNZ + 255) / 256, 256, 0, stream>>>(ii, deg);
  k_scan<<<1, 256, 0, stream>>>(deg, rowptr, cursor);
  k_fill<<<(NNZ + 255) / 256, 256, 0, stream>>>(ii, cursor, eids);

  const float* cu = Eu_a; const float* ci = Ei_a;
  float* nu = Eu_b; float* ni = Ei_b;
  for (int l = 0; l < 2; ++l) {
    k_feat<<<(N_TOT + 15) / 16, 256, 0, stream>>>(cu, ci, W, al, ar, feat, el, er);
    k_user_layer<<<(N_U * D) / 256, 256, 0, stream>>>(cu, ci, feat, el, er, vals, ii, nu, sEu, sGu);
    k_item_layer<<<(N_I * D) / 256, 256, 0, stream>>>(cu, ci, feat, el, er, vals, ui, rowptr, eids, ni, sEi, sGi);
    const float* tu = cu; cu = nu; nu = (float*)tu;
    const float* ti = ci; ci = ni; ni = (float*)ti;
  }

  k_lse_part<<<dim3(B / LQB, NSPU), 256, 0, stream>>>(sGu, uids, sEu, N_U, pmU, psU);
  k_lse_part<<<dim3(B / LQB, NSPI), 256, 0, stream>>>(sGi, iids, sEi, N_I, pmI, psI);
  k_reg<<<(N_TOT * D + 255) / 256, 256, 0, stream>>>(Eu0, Ei0, acc);
  k_small<<<B / 256, 256, 0, stream>>>(sEu, sEi, sGu, sGi, uids, iids, pos, neg,
                                       pmU, psU, pmI, psI, acc);
  k_final<<<1, 1, 0, stream>>>(acc, out);
}

// Round 3
// 939.035 us; speedup vs baseline: 6.5765x; 1.6073x over previous
//
#include <hip/hip_runtime.h>
#include <math.h>

#define N_U 30000
#define N_I 15000
#define N_TOT 45000
#define D 64
#define NNZ 480000
#define B 2048
#define INV_TEMP 5.0f
#define LOG_EPS -18.420680743952367f
#define NEG_SLOPE 0.2f
#define LAMBDA1 0.2f
#define LAMBDA2 1e-7f
#define NSPU 12
#define NSPI 6
#define ROWS_PER_SPLIT 2500

__device__ inline float wred(float v) {
#pragma unroll
  for (int o = 32; o > 0; o >>= 1) v += __shfl_down(v, o, 64);
  return v;
}

__device__ inline float leaky(float v) { return (v >= 0.f) ? v : NEG_SLOPE * v; }

// ---------------- init: Eu/Ei/sums from E0, zero deg + acc ----------------
__global__ void k_init(const float* __restrict__ Eu0, const float* __restrict__ Ei0,
                       float* Eu, float* Ei, float* sEu, float* sEi,
                       float* sGu, float* sGi, int* deg, float* acc) {
  int t = blockIdx.x * 256 + threadIdx.x;
  if (t < 16) acc[t] = 0.f;
  if (t < N_I) deg[t] = 0;
  if (t < N_U * D) {
    float v = Eu0[t]; Eu[t] = v; sEu[t] = v; sGu[t] = v;
  } else if (t < N_TOT * D) {
    int j = t - N_U * D;
    float v = Ei0[j]; Ei[j] = v; sEi[j] = v; sGi[j] = v;
  }
}

// ---------------- CSR build over item side ----------------
__global__ void k_deg(const int* __restrict__ ii, int* deg) {
  int e = blockIdx.x * 256 + threadIdx.x;
  if (e < NNZ) atomicAdd(&deg[ii[e]], 1);
}

__global__ void k_scan(const int* __restrict__ deg, int* rowptr, int* cursor) {
  __shared__ int buf[256];
  __shared__ int carry;
  int tid = threadIdx.x;
  if (tid == 0) carry = 0;
  __syncthreads();
  for (int base = 0; base < N_I; base += 256) {
    int v = (base + tid < N_I) ? deg[base + tid] : 0;
    buf[tid] = v;
    __syncthreads();
    for (int o = 1; o < 256; o <<= 1) {
      int x = (tid >= o) ? buf[tid - o] : 0;
      __syncthreads();
      buf[tid] += x;
      __syncthreads();
    }
    if (base + tid < N_I) {
      int excl = carry + buf[tid] - v;
      rowptr[base + tid] = excl;
      cursor[base + tid] = excl;
    }
    __syncthreads();
    if (tid == 255) carry += buf[255];
    __syncthreads();
  }
  if (tid == 0) rowptr[N_I] = carry;
}

__global__ void k_fill(const int* __restrict__ ii, int* cursor, int* eids) {
  int e = blockIdx.x * 256 + threadIdx.x;
  if (e < NNZ) {
    int pos = atomicAdd(&cursor[ii[e]], 1);
    eids[pos] = e;
  }
}

// ---------------- GAT: feat = h @ W, el/er head reductions ----------------
__global__ void k_feat(const float* __restrict__ Eu, const float* __restrict__ Ei,
                       const float* __restrict__ W, const float* __restrict__ al,
                       const float* __restrict__ ar,
                       float* __restrict__ feat, float* __restrict__ el, float* __restrict__ er) {
  __shared__ float Ws[64 * 64];
  __shared__ float hs[16][64];
  int tid = threadIdx.x;
  for (int t = tid; t < 1024; t += 256) ((float4*)Ws)[t] = ((const float4*)W)[t];
  int g = tid >> 6, c = tid & 63;
  int n0 = blockIdx.x * 16 + g * 4;
#pragma unroll
  for (int j = 0; j < 4; j++) {
    int node = n0 + j;
    if (node < N_TOT) {
      const float* src = (node < N_U) ? (Eu + (size_t)node * D) : (Ei + (size_t)(node - N_U) * D);
      hs[g * 4 + j][c] = src[c];
    }
  }
  __syncthreads();
  float a0 = 0.f, a1 = 0.f, a2 = 0.f, a3 = 0.f;
#pragma unroll 8
  for (int k = 0; k < 64; ++k) {
    float w = Ws[k * 64 + c];
    a0 = fmaf(hs[g * 4 + 0][k], w, a0);
    a1 = fmaf(hs[g * 4 + 1][k], w, a1);
    a2 = fmaf(hs[g * 4 + 2][k], w, a2);
    a3 = fmaf(hs[g * 4 + 3][k], w, a3);
  }
  float accs[4] = {a0, a1, a2, a3};
  float alc = al[c], arc = ar[c];
#pragma unroll
  for (int j = 0; j < 4; j++) {
    int node = n0 + j;
    if (node >= N_TOT) continue;
    feat[(size_t)node * D + c] = accs[j];
    float pl = accs[j] * alc;
    float pr = accs[j] * arc;
#pragma unroll
    for (int o = 8; o >= 1; o >>= 1) {
      pl += __shfl_down(pl, o, 16);
      pr += __shfl_down(pr, o, 16);
    }
    if ((c & 15) == 0) {
      el[node * 4 + (c >> 4)] = pl;
      er[node * 4 + (c >> 4)] = pr;
    }
  }
}

// ---------------- fused user-side layer ----------------
__global__ void k_user_layer(const float* __restrict__ curEu, const float* __restrict__ curEi,
                             const float* __restrict__ feat, const float* __restrict__ el,
                             const float* __restrict__ er, const float* __restrict__ vals,
                             const int* __restrict__ ii,
                             float* __restrict__ nxtEu, float* __restrict__ sEu,
                             float* __restrict__ sGu) {
  int t = blockIdx.x * 256 + threadIdx.x;
  int u = t >> 6, c = t & 63;
  if (u >= N_U) return;
  int h = c >> 4;
  float eru = er[u * 4 + h];
  float lself = leaky(el[u * 4 + h] + eru);
  float m = lself;
  float z = 0.f;
  int idx[16];
  float lv[16];
#pragma unroll
  for (int k = 0; k < 16; k++) {
    int e = u * 16 + k;
    int i = ii[e];
    idx[k] = i;
    z = fmaf(vals[e], curEi[(size_t)i * D + c], z);
    float l = leaky(el[(i + N_U) * 4 + h] + eru);
    lv[k] = l;
    m = fmaxf(m, l);
  }
  float aself = __expf(lself - m);
  float denom = aself;
  float o = aself * feat[(size_t)u * D + c];
#pragma unroll
  for (int k = 0; k < 16; k++) {
    float a = __expf(lv[k] - m);
    denom += a;
    o = fmaf(a, feat[(size_t)(idx[k] + N_U) * D + c], o);
  }
  o /= denom;
  float g = (o > 0.f) ? o : expm1f(o);
  size_t off = (size_t)u * D + c;
  float e_new = curEu[off] + z;
  nxtEu[off] = e_new;
  sEu[off] += e_new;
  sGu[off] += g;
}

// ---------------- fused item-side layer (CSR gather) ----------------
__global__ void k_item_layer(const float* __restrict__ curEu, const float* __restrict__ curEi,
                             const float* __restrict__ feat, const float* __restrict__ el,
                             const float* __restrict__ er, const float* __restrict__ vals,
                             const int* __restrict__ ui, const int* __restrict__ rowptr,
                             const int* __restrict__ eids,
                             float* __restrict__ nxtEi, float* __restrict__ sEi,
                             float* __restrict__ sGi) {
  int t = blockIdx.x * 256 + threadIdx.x;
  int i = t >> 6, c = t & 63;
  if (i >= N_I) return;
  int h = c >> 4;
  int node = N_U + i;
  float eri = er[node * 4 + h];
  float lself = leaky(el[node * 4 + h] + eri);
  float m = lself;
  float z = 0.f;
  int r0 = rowptr[i], r1 = rowptr[i + 1];
  for (int r = r0; r < r1; r++) {
    int e = eids[r];
    int u = ui[e];
    z = fmaf(vals[e], curEu[(size_t)u * D + c], z);
    float l = leaky(el[u * 4 + h] + eri);
    m = fmaxf(m, l);
  }
  float aself = __expf(lself - m);
  float denom = aself;
  float o = aself * feat[(size_t)node * D + c];
  for (int r = r0; r < r1; r++) {
    int e = eids[r];
    int u = ui[e];
    float a = __expf(leaky(el[u * 4 + h] + eri) - m);
    denom += a;
    o = fmaf(a, feat[(size_t)u * D + c], o);
  }
  o /= denom;
  float g = (o > 0.f) ? o : expm1f(o);
  size_t off = (size_t)i * D + c;
  float e_new = curEi[off] + z;
  nxtEi[off] = e_new;
  sEi[off] += e_new;
  sGi[off] += g;
}

// ---------------- tiled online logsumexp over G[ids[b]] . E[j] * invT ----------------
#define LQB 32
#define LTILE 128
#define LPAD 68

__global__ __launch_bounds__(256, 3) void k_lse_part(
    const float* __restrict__ G, const int* __restrict__ ids,
    const float* __restrict__ E, int n_rows,
    float* part_m, float* part_s) {
  __shared__ float qs[LQB * LPAD];
  __shared__ float es[LTILE * LPAD];
  int tid = threadIdx.x;
  int qb = blockIdx.x, split = blockIdx.y, nsplit = gridDim.y;

  for (int t = tid; t < LQB * 16; t += 256) {
    int q = t >> 4, c4 = (t & 15) << 2;
    int b = qb * LQB + q;
    float4 v = *(const float4*)(G + (size_t)ids[b] * D + c4);
    float* p = qs + q * LPAD + c4;
    p[0] = v.x; p[1] = v.y; p[2] = v.z; p[3] = v.w;
  }

  int row0 = split * ROWS_PER_SPLIT;
  int row_end = min(row0 + ROWS_PER_SPLIT, n_rows);
  int qq = tid & 7, jg = tid >> 3;
  float m0 = -INFINITY, m1 = -INFINITY, m2 = -INFINITY, m3 = -INFINITY;
  float s0 = 0.f, s1 = 0.f, s2 = 0.f, s3 = 0.f;

  const float* q0 = qs + (qq + 0) * LPAD;
  const float* q1 = qs + (qq + 8) * LPAD;
  const float* q2 = qs + (qq + 16) * LPAD;
  const float* q3 = qs + (qq + 24) * LPAD;

  for (int base = row0; base < row_end; base += LTILE) {
    __syncthreads();
    int nvalid = row_end - base;
    for (int t = tid; t < LTILE * 16; t += 256) {
      int r = t >> 4, c4 = (t & 15) << 2;
      float4 v = (r < nvalid) ? *(const float4*)(E + (size_t)(base + r) * D + c4)
                              : make_float4(0.f, 0.f, 0.f, 0.f);
      float* p = es + r * LPAD + c4;
      p[0] = v.x; p[1] = v.y; p[2] = v.z; p[3] = v.w;
    }
    __syncthreads();

    float dot[4][4];
#pragma unroll
    for (int a = 0; a < 4; a++)
#pragma unroll
      for (int b2 = 0; b2 < 4; b2++) dot[a][b2] = 0.f;

#pragma unroll 4
    for (int k = 0; k < 64; k += 4) {
      float4 qv[4], ev[4];
      qv[0] = *(const float4*)(q0 + k);
      qv[1] = *(const float4*)(q1 + k);
      qv[2] = *(const float4*)(q2 + k);
      qv[3] = *(const float4*)(q3 + k);
#pragma unroll
      for (int jj = 0; jj < 4; jj++) ev[jj] = *(const float4*)(es + (jg + 32 * jj) * LPAD + k);
#pragma unroll
      for (int qi = 0; qi < 4; qi++)
#pragma unroll
        for (int jj = 0; jj < 4; jj++) {
          dot[qi][jj] = fmaf(qv[qi].x, ev[jj].x, dot[qi][jj]);
          dot[qi][jj] = fmaf(qv[qi].y, ev[jj].y, dot[qi][jj]);
          dot[qi][jj] = fmaf(qv[qi].z, ev[jj].z, dot[qi][jj]);
          dot[qi][jj] = fmaf(qv[qi].w, ev[jj].w, dot[qi][jj]);
        }
    }

#pragma unroll
    for (int jj = 0; jj < 4; jj++) {
      if (jg + 32 * jj < nvalid) {
        float d;
        d = dot[0][jj] * INV_TEMP; if (d > m0) { s0 = s0 * __expf(m0 - d) + 1.f; m0 = d; } else s0 += __expf(d - m0);
        d = dot[1][jj] * INV_TEMP; if (d > m1) { s1 = s1 * __expf(m1 - d) + 1.f; m1 = d; } else s1 += __expf(d - m1);
        d = dot[2][jj] * INV_TEMP; if (d > m2) { s2 = s2 * __expf(m2 - d) + 1.f; m2 = d; } else s2 += __expf(d - m2);
        d = dot[3][jj] * INV_TEMP; if (d > m3) { s3 = s3 * __expf(m3 - d) + 1.f; m3 = d; } else s3 += __expf(d - m3);
      }
    }
  }

  __syncthreads();
  float* rm = es;
  float* rs = es + 1024;
  rm[(qq + 0) * 32 + jg] = m0;  rs[(qq + 0) * 32 + jg] = s0;
  rm[(qq + 8) * 32 + jg] = m1;  rs[(qq + 8) * 32 + jg] = s1;
  rm[(qq + 16) * 32 + jg] = m2; rs[(qq + 16) * 32 + jg] = s2;
  rm[(qq + 24) * 32 + jg] = m3; rs[(qq + 24) * 32 + jg] = s3;
  __syncthreads();
  if (tid < 32) {
    float mm = -INFINITY, ss = 0.f;
    for (int j = 0; j < 32; j++) {
      float mj = rm[tid * 32 + j];
      if (mj == -INFINITY) continue;
      float sj = rs[tid * 32 + j];
      if (mj > mm) { ss = ss * __expf(mm - mj) + sj; mm = mj; }
      else ss += sj * __expf(mj - mm);
    }
    int b = qb * LQB + tid;
    part_m[(size_t)b * nsplit + split] = mm;
    part_s[(size_t)b * nsplit + split] = ss;
  }
}

// ---------------- L2 regularization reduce: grid-stride, 1 atomic/block ----------------
__global__ void k_reg(const float* __restrict__ Eu0, const float* __restrict__ Ei0, float* acc) {
  __shared__ float red[4];
  int tid = threadIdx.x;
  float s = 0.f;
  const float4* A = (const float4*)Eu0;   // N_U*16 float4
  const float4* Bp = (const float4*)Ei0;  // N_I*16 float4
  const int nA = N_U * 16, nTot = N_TOT * 16;
  for (int t = blockIdx.x * 256 + tid; t < nTot; t += 256 * 256) {
    float4 v = (t < nA) ? A[t] : Bp[t - nA];
    s += v.x * v.x + v.y * v.y + v.z * v.z + v.w * v.w;
  }
  s = wred(s);
  if ((tid & 63) == 0) red[tid >> 6] = s;
  __syncthreads();
  if (tid == 0) unsafeAtomicAdd(acc + 5, red[0] + red[1] + red[2] + red[3]);
}

// ---------------- per-sample losses: lse combine, pos dots, BPR ----------------
__global__ void k_small(const float* __restrict__ sEu, const float* __restrict__ sEi,
                        const float* __restrict__ sGu, const float* __restrict__ sGi,
                        const int* __restrict__ uids, const int* __restrict__ iids,
                        const int* __restrict__ pos, const int* __restrict__ neg,
                        const float* __restrict__ pmU, const float* __restrict__ psU,
                        const float* __restrict__ pmI, const float* __restrict__ psI,
                        float* acc) {
  int b = blockIdx.x * 256 + threadIdx.x;
  float du = 0.f, di = 0.f, nu = 0.f, ni = 0.f, bpr = 0.f;
  if (b < B) {
    float mm = -INFINITY, ss = 0.f;
    for (int s2 = 0; s2 < NSPU; s2++) {
      float mj = pmU[b * NSPU + s2];
      if (mj == -INFINITY) continue;
      float sj = psU[b * NSPU + s2];
      if (mj > mm) { ss = ss * __expf(mm - mj) + sj; mm = mj; } else ss += sj * __expf(mj - mm);
    }
    float lseu = mm + logf(ss);
    mm = -INFINITY; ss = 0.f;
    for (int s2 = 0; s2 < NSPI; s2++) {
      float mj = pmI[b * NSPI + s2];
      if (mj == -INFINITY) continue;
      float sj = psI[b * NSPI + s2];
      if (mj > mm) { ss = ss * __expf(mm - mj) + sj; mm = mj; } else ss += sj * __expf(mj - mm);
    }
    float lsei = mm + logf(ss);
    nu = fmaxf(lseu, LOG_EPS) + log1pf(expf(-fabsf(lseu - LOG_EPS)));
    ni = fmaxf(lsei, LOG_EPS) + log1pf(expf(-fabsf(lsei - LOG_EPS)));

    int u = uids[b], it = iids[b], p = pos[b], ng = neg[b];
    const float4* gu = (const float4*)(sGu + (size_t)u * D);
    const float4* eu = (const float4*)(sEu + (size_t)u * D);
    const float4* gi = (const float4*)(sGi + (size_t)it * D);
    const float4* ei = (const float4*)(sEi + (size_t)it * D);
    const float4* ep = (const float4*)(sEi + (size_t)p * D);
    const float4* en = (const float4*)(sEi + (size_t)ng * D);
    float diff = 0.f;
#pragma unroll
    for (int k = 0; k < 16; k++) {
      float4 a = gu[k], b4 = eu[k];
      du += a.x * b4.x + a.y * b4.y + a.z * b4.z + a.w * b4.w;
      float4 c = gi[k], d4 = ei[k];
      di += c.x * d4.x + c.y * d4.y + c.z * d4.z + c.w * d4.w;
      float4 e = ep[k], f = en[k];
      diff += b4.x * (e.x - f.x) + b4.y * (e.y - f.y) + b4.z * (e.z - f.z) + b4.w * (e.w - f.w);
    }
    bpr = (diff > 0.f) ? log1pf(expf(-diff)) : (-diff + log1pf(expf(diff)));
  }
  du = wred(du); di = wred(di); nu = wred(nu); ni = wred(ni); bpr = wred(bpr);
  if ((threadIdx.x & 63) == 0) {
    unsafeAtomicAdd(acc + 0, du);
    unsafeAtomicAdd(acc + 1, di);
    unsafeAtomicAdd(acc + 2, nu);
    unsafeAtomicAdd(acc + 3, ni);
    unsafeAtomicAdd(acc + 4, bpr);
  }
}

// ---------------- finalize ----------------
__global__ void k_final(const float* __restrict__ acc, float* __restrict__ out) {
  float pos_score = (acc[0] + acc[1]) * (INV_TEMP / (float)B);
  float neg_score = (acc[2] + acc[3]) / (float)B;
  float loss_s = neg_score - pos_score;
  float loss_r = acc[4] / (float)B;
  float reg = LAMBDA2 * acc[5];
  out[0] = loss_r + LAMBDA1 * loss_s + reg;
  out[1] = loss_r;
  out[2] = LAMBDA1 * loss_s;
}

extern "C" void kernel_launch(void* const* d_in, const int* in_sizes, int n_in,
                              void* d_out, int out_size, void* d_ws, size_t ws_size,
                              hipStream_t stream) {
  const float* Eu0  = (const float*)d_in[0];
  const float* Ei0  = (const float*)d_in[1];
  const float* vals = (const float*)d_in[2];
  const float* W    = (const float*)d_in[3];
  const float* al   = (const float*)d_in[4];
  const float* ar   = (const float*)d_in[5];
  const int* ui     = (const int*)d_in[6];
  const int* ii     = (const int*)d_in[7];
  const int* uids   = (const int*)d_in[10];
  const int* iids   = (const int*)d_in[11];
  const int* pos    = (const int*)d_in[12];
  const int* neg    = (const int*)d_in[13];
  float* out = (float*)d_out;

  float* w = (float*)d_ws;
  size_t off = 0;
  float* Eu_a = w + off; off += (size_t)N_U * D;
  float* Ei_a = w + off; off += (size_t)N_I * D;
  float* Eu_b = w + off; off += (size_t)N_U * D;
  float* Ei_b = w + off; off += (size_t)N_I * D;
  float* sEu  = w + off; off += (size_t)N_U * D;
  float* sEi  = w + off; off += (size_t)N_I * D;
  float* sGu  = w + off; off += (size_t)N_U * D;
  float* sGi  = w + off; off += (size_t)N_I * D;
  float* feat = w + off; off += (size_t)N_TOT * D;
  float* el   = w + off; off += (size_t)N_TOT * 4;
  float* er   = w + off; off += (size_t)N_TOT * 4;
  float* pmU  = w + off; off += (size_t)B * NSPU;
  float* psU  = w + off; off += (size_t)B * NSPU;
  float* pmI  = w + off; off += (size_t)B * NSPI;
  float* psI  = w + off; off += (size_t)B * NSPI;
  float* acc  = w + off; off += 16;
  int* iw = (int*)(w + off);
  int* deg    = iw;
  int* cursor = iw + N_I;
  int* rowptr = iw + 2 * N_I;
  int* eids   = iw + 3 * N_I + 1;

  k_init<<<(N_TOT * D + 255) / 256, 256, 0, stream>>>(Eu0, Ei0, Eu_a, Ei_a, sEu, sEi, sGu, sGi, deg, acc);
  k_deg<<<(NNZ + 255) / 256, 256, 0, stream>>>(ii, deg);
  k_scan<<<1, 256, 0, stream>>>(deg, rowptr, cursor);
  k_fill<<<(NNZ + 255) / 256, 256, 0, stream>>>(ii, cursor, eids);

  const float* cu = Eu_a; const float* ci = Ei_a;
  float* nu = Eu_b; float* ni = Ei_b;
  for (int l = 0; l < 2; ++l) {
    k_feat<<<(N_TOT + 15) / 16, 256, 0, stream>>>(cu, ci, W, al, ar, feat, el, er);
    k_user_layer<<<(N_U * D) / 256, 256, 0, stream>>>(cu, ci, feat, el, er, vals, ii, nu, sEu, sGu);
    k_item_layer<<<(N_I * D) / 256, 256, 0, stream>>>(cu, ci, feat, el, er, vals, ui, rowptr, eids, ni, sEi, sGi);
    const float* tu = cu; cu = nu; nu = (float*)tu;
    const float* ti = ci; ci = ni; ni = (float*)ti;
  }

  k_lse_part<<<dim3(B / LQB, NSPU), 256, 0, stream>>>(sGu, uids, sEu, N_U, pmU, psU);
  k_lse_part<<<dim3(B / LQB, NSPI), 256, 0, stream>>>(sGi, iids, sEi, N_I, pmI, psI);
  k_reg<<<256, 256, 0, stream>>>(Eu0, Ei0, acc);
  k_small<<<B / 256, 256, 0, stream>>>(sEu, sEi, sGu, sGi, uids, iids, pos, neg,
                                       pmU, psU, pmI, psI, acc);
  k_final<<<1, 1, 0, stream>>>(acc, out);
}

// Round 4
// 750.603 us; speedup vs baseline: 8.2274x; 1.2510x over previous
//
#include <hip/hip_runtime.h>
#include <math.h>

#define N_U 30000
#define N_I 15000
#define N_TOT 45000
#define D 64
#define NNZ 480000
#define B 2048
#define INV_TEMP 5.0f
#define LOG_EPS -18.420680743952367f
#define NEG_SLOPE 0.2f
#define LAMBDA1 0.2f
#define LAMBDA2 1e-7f

// MFMA-lse config
#define NSP 64
#define RSP_U 469      // ceil(30000/64); 64*469 = 30016
#define RSP_I 235      // ceil(15000/64); 64*235 = 15040
#define PAD_U 30016
#define PAD_I 15040
#define SCALE_LOG2 7.2134752044448170f  // INV_TEMP * log2(e)
#define LN2F 0.6931471805599453f

typedef __attribute__((ext_vector_type(8))) short short8;
typedef __attribute__((ext_vector_type(4))) float f32x4;

__device__ inline float wred(float v) {
#pragma unroll
  for (int o = 32; o > 0; o >>= 1) v += __shfl_down(v, o, 64);
  return v;
}

__device__ inline float leaky(float v) { return (v >= 0.f) ? v : NEG_SLOPE * v; }

__device__ inline unsigned short f2bf(float x) {
  unsigned u = __float_as_uint(x);
  unsigned r = u + 0x7FFFu + ((u >> 16) & 1u);
  return (unsigned short)(r >> 16);
}
__device__ inline float bf2f(unsigned short h) {
  return __uint_as_float(((unsigned)h) << 16);
}

// ---------------- init ----------------
__global__ void k_init(const float* __restrict__ Eu0, const float* __restrict__ Ei0,
                       float* Eu, float* Ei, float* sEu, float* sEi,
                       float* sGu, float* sGi, int* deg, float* acc) {
  int t = blockIdx.x * 256 + threadIdx.x;
  if (t < 16) acc[t] = 0.f;
  if (t < N_I) deg[t] = 0;
  if (t < N_U * D) {
    float v = Eu0[t]; Eu[t] = v; sEu[t] = v; sGu[t] = v;
  } else if (t < N_TOT * D) {
    int j = t - N_U * D;
    float v = Ei0[j]; Ei[j] = v; sEi[j] = v; sGi[j] = v;
  }
}

// ---------------- CSR build over item side ----------------
__global__ void k_deg(const int* __restrict__ ii, int* deg) {
  int e = blockIdx.x * 256 + threadIdx.x;
  if (e < NNZ) atomicAdd(&deg[ii[e]], 1);
}

__global__ void k_scan(const int* __restrict__ deg, int* rowptr, int* cursor) {
  __shared__ int buf[256];
  __shared__ int carry;
  int tid = threadIdx.x;
  if (tid == 0) carry = 0;
  __syncthreads();
  for (int base = 0; base < N_I; base += 256) {
    int v = (base + tid < N_I) ? deg[base + tid] : 0;
    buf[tid] = v;
    __syncthreads();
    for (int o = 1; o < 256; o <<= 1) {
      int x = (tid >= o) ? buf[tid - o] : 0;
      __syncthreads();
      buf[tid] += x;
      __syncthreads();
    }
    if (base + tid < N_I) {
      int excl = carry + buf[tid] - v;
      rowptr[base + tid] = excl;
      cursor[base + tid] = excl;
    }
    __syncthreads();
    if (tid == 255) carry += buf[255];
    __syncthreads();
  }
  if (tid == 0) rowptr[N_I] = carry;
}

__global__ void k_fill(const int* __restrict__ ii, int* cursor, int* eids) {
  int e = blockIdx.x * 256 + threadIdx.x;
  if (e < NNZ) {
    int pos = atomicAdd(&cursor[ii[e]], 1);
    eids[pos] = e;
  }
}

// ---------------- GAT: feat = h @ W, el/er head reductions ----------------
__global__ void k_feat(const float* __restrict__ Eu, const float* __restrict__ Ei,
                       const float* __restrict__ W, const float* __restrict__ al,
                       const float* __restrict__ ar,
                       float* __restrict__ feat, float* __restrict__ el, float* __restrict__ er) {
  __shared__ float Ws[64 * 64];
  __shared__ float hs[16][64];
  int tid = threadIdx.x;
  for (int t = tid; t < 1024; t += 256) ((float4*)Ws)[t] = ((const float4*)W)[t];
  int g = tid >> 6, c = tid & 63;
  int n0 = blockIdx.x * 16 + g * 4;
#pragma unroll
  for (int j = 0; j < 4; j++) {
    int node = n0 + j;
    if (node < N_TOT) {
      const float* src = (node < N_U) ? (Eu + (size_t)node * D) : (Ei + (size_t)(node - N_U) * D);
      hs[g * 4 + j][c] = src[c];
    }
  }
  __syncthreads();
  float a0 = 0.f, a1 = 0.f, a2 = 0.f, a3 = 0.f;
#pragma unroll 8
  for (int k = 0; k < 64; ++k) {
    float w = Ws[k * 64 + c];
    a0 = fmaf(hs[g * 4 + 0][k], w, a0);
    a1 = fmaf(hs[g * 4 + 1][k], w, a1);
    a2 = fmaf(hs[g * 4 + 2][k], w, a2);
    a3 = fmaf(hs[g * 4 + 3][k], w, a3);
  }
  float accs[4] = {a0, a1, a2, a3};
  float alc = al[c], arc = ar[c];
#pragma unroll
  for (int j = 0; j < 4; j++) {
    int node = n0 + j;
    if (node >= N_TOT) continue;
    feat[(size_t)node * D + c] = accs[j];
    float pl = accs[j] * alc;
    float pr = accs[j] * arc;
#pragma unroll
    for (int o = 8; o >= 1; o >>= 1) {
      pl += __shfl_down(pl, o, 16);
      pr += __shfl_down(pr, o, 16);
    }
    if ((c & 15) == 0) {
      el[node * 4 + (c >> 4)] = pl;
      er[node * 4 + (c >> 4)] = pr;
    }
  }
}

// ---------------- fused user-side layer ----------------
__global__ void k_user_layer(const float* __restrict__ curEu, const float* __restrict__ curEi,
                             const float* __restrict__ feat, const float* __restrict__ el,
                             const float* __restrict__ er, const float* __restrict__ vals,
                             const int* __restrict__ ii,
                             float* __restrict__ nxtEu, float* __restrict__ sEu,
                             float* __restrict__ sGu) {
  int t = blockIdx.x * 256 + threadIdx.x;
  int u = t >> 6, c = t & 63;
  if (u >= N_U) return;
  int h = c >> 4;
  float eru = er[u * 4 + h];
  float lself = leaky(el[u * 4 + h] + eru);
  float m = lself;
  float z = 0.f;
  int idx[16];
  float lv[16];
#pragma unroll
  for (int k = 0; k < 16; k++) {
    int e = u * 16 + k;
    int i = ii[e];
    idx[k] = i;
    z = fmaf(vals[e], curEi[(size_t)i * D + c], z);
    float l = leaky(el[(i + N_U) * 4 + h] + eru);
    lv[k] = l;
    m = fmaxf(m, l);
  }
  float aself = __expf(lself - m);
  float denom = aself;
  float o = aself * feat[(size_t)u * D + c];
#pragma unroll
  for (int k = 0; k < 16; k++) {
    float a = __expf(lv[k] - m);
    denom += a;
    o = fmaf(a, feat[(size_t)(idx[k] + N_U) * D + c], o);
  }
  o /= denom;
  float g = (o > 0.f) ? o : expm1f(o);
  size_t off = (size_t)u * D + c;
  float e_new = curEu[off] + z;
  nxtEu[off] = e_new;
  sEu[off] += e_new;
  sGu[off] += g;
}

// ---------------- fused item-side layer (CSR gather) ----------------
__global__ void k_item_layer(const float* __restrict__ curEu, const float* __restrict__ curEi,
                             const float* __restrict__ feat, const float* __restrict__ el,
                             const float* __restrict__ er, const float* __restrict__ vals,
                             const int* __restrict__ ui, const int* __restrict__ rowptr,
                             const int* __restrict__ eids,
                             float* __restrict__ nxtEi, float* __restrict__ sEi,
                             float* __restrict__ sGi) {
  int t = blockIdx.x * 256 + threadIdx.x;
  int i = t >> 6, c = t & 63;
  if (i >= N_I) return;
  int h = c >> 4;
  int node = N_U + i;
  float eri = er[node * 4 + h];
  float lself = leaky(el[node * 4 + h] + eri);
  float m = lself;
  float z = 0.f;
  int r0 = rowptr[i], r1 = rowptr[i + 1];
  for (int r = r0; r < r1; r++) {
    int e = eids[r];
    int u = ui[e];
    z = fmaf(vals[e], curEu[(size_t)u * D + c], z);
    float l = leaky(el[u * 4 + h] + eri);
    m = fmaxf(m, l);
  }
  float aself = __expf(lself - m);
  float denom = aself;
  float o = aself * feat[(size_t)node * D + c];
  for (int r = r0; r < r1; r++) {
    int e = eids[r];
    int u = ui[e];
    float a = __expf(leaky(el[u * 4 + h] + eri) - m);
    denom += a;
    o = fmaf(a, feat[(size_t)u * D + c], o);
  }
  o /= denom;
  float g = (o > 0.f) ? o : expm1f(o);
  size_t off = (size_t)i * D + c;
  float e_new = curEi[off] + z;
  nxtEi[off] = e_new;
  sEi[off] += e_new;
  sGi[off] += g;
}

// ---------------- split-bf16 conversion: E matrices (with zero pad rows) ----------------
__global__ void k_cvt_e(const float* __restrict__ sEu, const float* __restrict__ sEi,
                        unsigned short* __restrict__ EuH, unsigned short* __restrict__ EuL,
                        unsigned short* __restrict__ EiH, unsigned short* __restrict__ EiL) {
  int t = blockIdx.x * 256 + threadIdx.x;
  const int nu = PAD_U * 64;
  const int ntot = (PAD_U + PAD_I) * 64;
  if (t >= ntot) return;
  if (t < nu) {
    int row = t >> 6;
    float x = (row < N_U) ? sEu[t] : 0.f;
    unsigned short hi = f2bf(x);
    EuH[t] = hi;
    EuL[t] = f2bf(x - bf2f(hi));
  } else {
    int t2 = t - nu;
    int row = t2 >> 6;
    float x = (row < N_I) ? sEi[t2] : 0.f;
    unsigned short hi = f2bf(x);
    EiH[t2] = hi;
    EiL[t2] = f2bf(x - bf2f(hi));
  }
}

// ---------------- split-bf16 conversion: gathered query matrices ----------------
__global__ void k_cvt_q(const float* __restrict__ sGu, const float* __restrict__ sGi,
                        const int* __restrict__ uids, const int* __restrict__ iids,
                        unsigned short* __restrict__ QuH, unsigned short* __restrict__ QuL,
                        unsigned short* __restrict__ QiH, unsigned short* __restrict__ QiL) {
  int t = blockIdx.x * 256 + threadIdx.x;   // 0 .. 2*B*64
  int side = t >> 17;                       // B*64 = 131072 = 2^17
  int t2 = t & (B * 64 - 1);
  int b = t2 >> 6, k = t2 & 63;
  int id = side ? iids[b] : uids[b];
  float x = side ? sGi[(size_t)id * 64 + k] : sGu[(size_t)id * 64 + k];
  unsigned short hi = f2bf(x);
  unsigned short lo = f2bf(x - bf2f(hi));
  if (side) { QiH[t2] = hi; QiL[t2] = lo; }
  else      { QuH[t2] = hi; QuL[t2] = lo; }
}

// ---------------- MFMA logsumexp: scores = (Q . E^T) * INV_TEMP, online softmax ----------------
// split-bf16: q.e ~= qh.eh + ql.eh + qh.el  (lo*lo dropped, ~1.5e-5 rel)
// grid (16, NSP); block 256 = 4 waves; 128 queries/block, wave owns 2 q-tiles of 16.
__global__ __launch_bounds__(256) void k_lse_mfma(
    const unsigned short* __restrict__ Qhi, const unsigned short* __restrict__ Qlo,
    const unsigned short* __restrict__ Ehi, const unsigned short* __restrict__ Elo,
    int n_rows, int rows_per_split,
    float* __restrict__ part_m, float* __restrict__ part_s) {
  int tid = threadIdx.x;
  int wave = tid >> 6, lane = tid & 63;
  int l15 = lane & 15, quad = lane >> 4;
  int qt0 = blockIdx.x * 128 + wave * 32;
  int split = blockIdx.y;
  int row0 = split * rows_per_split;
  int row_end = min(row0 + rows_per_split, n_rows);

  // A fragments (queries), held for the whole kernel: [tile][k-chunk]
  short8 ah[2][2], al[2][2];
#pragma unroll
  for (int t = 0; t < 2; t++)
#pragma unroll
    for (int c = 0; c < 2; c++) {
      size_t idx = (size_t)(qt0 + t * 16 + l15) * 64 + c * 32 + quad * 8;
      ah[t][c] = *(const short8*)(Qhi + idx);
      al[t][c] = *(const short8*)(Qlo + idx);
    }

  float mst[2][4], sst[2][4];
#pragma unroll
  for (int t = 0; t < 2; t++)
#pragma unroll
    for (int g = 0; g < 4; g++) { mst[t][g] = -1e30f; sst[t][g] = 0.f; }

  for (int rb = row0; rb < row_end; rb += 16) {
    int r = rb + l15;
    bool valid = r < row_end;
    size_t eb = (size_t)r * 64 + quad * 8;   // pad rows guarantee in-bounds
    short8 bh0 = *(const short8*)(Ehi + eb);
    short8 bh1 = *(const short8*)(Ehi + eb + 32);
    short8 bl0 = *(const short8*)(Elo + eb);
    short8 bl1 = *(const short8*)(Elo + eb + 32);

#pragma unroll
    for (int t = 0; t < 2; t++) {
      f32x4 acc = {0.f, 0.f, 0.f, 0.f};
      acc = __builtin_amdgcn_mfma_f32_16x16x32_bf16(ah[t][0], bh0, acc, 0, 0, 0);
      acc = __builtin_amdgcn_mfma_f32_16x16x32_bf16(ah[t][1], bh1, acc, 0, 0, 0);
      acc = __builtin_amdgcn_mfma_f32_16x16x32_bf16(al[t][0], bh0, acc, 0, 0, 0);
      acc = __builtin_amdgcn_mfma_f32_16x16x32_bf16(al[t][1], bh1, acc, 0, 0, 0);
      acc = __builtin_amdgcn_mfma_f32_16x16x32_bf16(ah[t][0], bl0, acc, 0, 0, 0);
      acc = __builtin_amdgcn_mfma_f32_16x16x32_bf16(ah[t][1], bl1, acc, 0, 0, 0);
      // online softmax in log2 domain; C/D: col(r)=lane&15, row(q)=quad*4+g
#pragma unroll
      for (int g = 0; g < 4; g++) {
        float d = valid ? acc[g] * SCALE_LOG2 : -2e30f;
        float mo = mst[t][g];
        float delta = d - mo;
        float e = exp2f(-fabsf(delta));
        bool gt = delta > 0.f;
        sst[t][g] = gt ? (sst[t][g] * e + 1.f) : (sst[t][g] + e);
        mst[t][g] = gt ? d : mo;
      }
    }
  }

  // merge across the 16 row-lanes (same quad group)
#pragma unroll
  for (int off = 1; off < 16; off <<= 1) {
#pragma unroll
    for (int t = 0; t < 2; t++)
#pragma unroll
      for (int g = 0; g < 4; g++) {
        float om = __shfl_xor(mst[t][g], off, 64);
        float os = __shfl_xor(sst[t][g], off, 64);
        float mn = fmaxf(mst[t][g], om);
        sst[t][g] = sst[t][g] * exp2f(mst[t][g] - mn) + os * exp2f(om - mn);
        mst[t][g] = mn;
      }
  }
  if (l15 == 0) {
#pragma unroll
    for (int t = 0; t < 2; t++)
#pragma unroll
      for (int g = 0; g < 4; g++) {
        int q = qt0 + t * 16 + quad * 4 + g;
        part_m[(size_t)q * NSP + split] = mst[t][g];
        part_s[(size_t)q * NSP + split] = sst[t][g];
      }
  }
}

// ---------------- L2 regularization reduce ----------------
__global__ void k_reg(const float* __restrict__ Eu0, const float* __restrict__ Ei0, float* acc) {
  __shared__ float red[4];
  int tid = threadIdx.x;
  float s = 0.f;
  const float4* A = (const float4*)Eu0;
  const float4* Bp = (const float4*)Ei0;
  const int nA = N_U * 16, nTot = N_TOT * 16;
  for (int t = blockIdx.x * 256 + tid; t < nTot; t += 256 * 256) {
    float4 v = (t < nA) ? A[t] : Bp[t - nA];
    s += v.x * v.x + v.y * v.y + v.z * v.z + v.w * v.w;
  }
  s = wred(s);
  if ((tid & 63) == 0) red[tid >> 6] = s;
  __syncthreads();
  if (tid == 0) unsafeAtomicAdd(acc + 5, red[0] + red[1] + red[2] + red[3]);
}

// ---------------- per-sample losses: lse combine (log2 partials), pos dots, BPR ----------------
__global__ void k_small(const float* __restrict__ sEu, const float* __restrict__ sEi,
                        const float* __restrict__ sGu, const float* __restrict__ sGi,
                        const int* __restrict__ uids, const int* __restrict__ iids,
                        const int* __restrict__ pos, const int* __restrict__ neg,
                        const float* __restrict__ pmU, const float* __restrict__ psU,
                        const float* __restrict__ pmI, const float* __restrict__ psI,
                        float* acc) {
  int b = blockIdx.x * 256 + threadIdx.x;
  float du = 0.f, di = 0.f, nu = 0.f, ni = 0.f, bpr = 0.f;
  if (b < B) {
    float mm = -1e30f, ss = 0.f;
    for (int s2 = 0; s2 < NSP; s2++) {
      float mj = pmU[(size_t)b * NSP + s2];
      float sj = psU[(size_t)b * NSP + s2];
      float mn = fmaxf(mm, mj);
      ss = ss * exp2f(mm - mn) + sj * exp2f(mj - mn);
      mm = mn;
    }
    float lseu = mm * LN2F + logf(ss);
    mm = -1e30f; ss = 0.f;
    for (int s2 = 0; s2 < NSP; s2++) {
      float mj = pmI[(size_t)b * NSP + s2];
      float sj = psI[(size_t)b * NSP + s2];
      float mn = fmaxf(mm, mj);
      ss = ss * exp2f(mm - mn) + sj * exp2f(mj - mn);
      mm = mn;
    }
    float lsei = mm * LN2F + logf(ss);
    nu = fmaxf(lseu, LOG_EPS) + log1pf(expf(-fabsf(lseu - LOG_EPS)));
    ni = fmaxf(lsei, LOG_EPS) + log1pf(expf(-fabsf(lsei - LOG_EPS)));

    int u = uids[b], it = iids[b], p = pos[b], ng = neg[b];
    const float4* gu = (const float4*)(sGu + (size_t)u * D);
    const float4* eu = (const float4*)(sEu + (size_t)u * D);
    const float4* gi = (const float4*)(sGi + (size_t)it * D);
    const float4* ei = (const float4*)(sEi + (size_t)it * D);
    const float4* ep = (const float4*)(sEi + (size_t)p * D);
    const float4* en = (const float4*)(sEi + (size_t)ng * D);
    float diff = 0.f;
#pragma unroll
    for (int k = 0; k < 16; k++) {
      float4 a = gu[k], b4 = eu[k];
      du += a.x * b4.x + a.y * b4.y + a.z * b4.z + a.w * b4.w;
      float4 c = gi[k], d4 = ei[k];
      di += c.x * d4.x + c.y * d4.y + c.z * d4.z + c.w * d4.w;
      float4 e = ep[k], f = en[k];
      diff += b4.x * (e.x - f.x) + b4.y * (e.y - f.y) + b4.z * (e.z - f.z) + b4.w * (e.w - f.w);
    }
    bpr = (diff > 0.f) ? log1pf(expf(-diff)) : (-diff + log1pf(expf(diff)));
  }
  du = wred(du); di = wred(di); nu = wred(nu); ni = wred(ni); bpr = wred(bpr);
  if ((threadIdx.x & 63) == 0) {
    unsafeAtomicAdd(acc + 0, du);
    unsafeAtomicAdd(acc + 1, di);
    unsafeAtomicAdd(acc + 2, nu);
    unsafeAtomicAdd(acc + 3, ni);
    unsafeAtomicAdd(acc + 4, bpr);
  }
}

// ---------------- finalize ----------------
__global__ void k_final(const float* __restrict__ acc, float* __restrict__ out) {
  float pos_score = (acc[0] + acc[1]) * (INV_TEMP / (float)B);
  float neg_score = (acc[2] + acc[3]) / (float)B;
  float loss_s = neg_score - pos_score;
  float loss_r = acc[4] / (float)B;
  float reg = LAMBDA2 * acc[5];
  out[0] = loss_r + LAMBDA1 * loss_s + reg;
  out[1] = loss_r;
  out[2] = LAMBDA1 * loss_s;
}

extern "C" void kernel_launch(void* const* d_in, const int* in_sizes, int n_in,
                              void* d_out, int out_size, void* d_ws, size_t ws_size,
                              hipStream_t stream) {
  const float* Eu0  = (const float*)d_in[0];
  const float* Ei0  = (const float*)d_in[1];
  const float* vals = (const float*)d_in[2];
  const float* W    = (const float*)d_in[3];
  const float* al   = (const float*)d_in[4];
  const float* ar   = (const float*)d_in[5];
  const int* ui     = (const int*)d_in[6];
  const int* ii     = (const int*)d_in[7];
  const int* uids   = (const int*)d_in[10];
  const int* iids   = (const int*)d_in[11];
  const int* pos    = (const int*)d_in[12];
  const int* neg    = (const int*)d_in[13];
  float* out = (float*)d_out;

  char* base = (char*)d_ws;
  size_t off = 0;
  auto alloc = [&](size_t bytes) -> void* {
    void* p = base + off;
    off = (off + bytes + 255) & ~(size_t)255;
    return p;
  };
  float* Eu_a = (float*)alloc((size_t)N_U * D * 4);
  float* Ei_a = (float*)alloc((size_t)N_I * D * 4);
  float* Eu_b = (float*)alloc((size_t)N_U * D * 4);
  float* Ei_b = (float*)alloc((size_t)N_I * D * 4);
  float* sEu  = (float*)alloc((size_t)N_U * D * 4);
  float* sEi  = (float*)alloc((size_t)N_I * D * 4);
  float* sGu  = (float*)alloc((size_t)N_U * D * 4);
  float* sGi  = (float*)alloc((size_t)N_I * D * 4);
  float* feat = (float*)alloc((size_t)N_TOT * D * 4);
  float* el   = (float*)alloc((size_t)N_TOT * 4 * 4);
  float* er   = (float*)alloc((size_t)N_TOT * 4 * 4);
  float* pmU  = (float*)alloc((size_t)B * NSP * 4);
  float* psU  = (float*)alloc((size_t)B * NSP * 4);
  float* pmI  = (float*)alloc((size_t)B * NSP * 4);
  float* psI  = (float*)alloc((size_t)B * NSP * 4);
  float* acc  = (float*)alloc(16 * 4);
  int* deg    = (int*)alloc((size_t)N_I * 4);
  int* cursor = (int*)alloc((size_t)N_I * 4);
  int* rowptr = (int*)alloc((size_t)(N_I + 1) * 4);
  int* eids   = (int*)alloc((size_t)NNZ * 4);
  unsigned short* EuH = (unsigned short*)alloc((size_t)PAD_U * 64 * 2);
  unsigned short* EuL = (unsigned short*)alloc((size_t)PAD_U * 64 * 2);
  unsigned short* EiH = (unsigned short*)alloc((size_t)PAD_I * 64 * 2);
  unsigned short* EiL = (unsigned short*)alloc((size_t)PAD_I * 64 * 2);
  unsigned short* QuH = (unsigned short*)alloc((size_t)B * 64 * 2);
  unsigned short* QuL = (unsigned short*)alloc((size_t)B * 64 * 2);
  unsigned short* QiH = (unsigned short*)alloc((size_t)B * 64 * 2);
  unsigned short* QiL = (unsigned short*)alloc((size_t)B * 64 * 2);

  k_init<<<(N_TOT * D + 255) / 256, 256, 0, stream>>>(Eu0, Ei0, Eu_a, Ei_a, sEu, sEi, sGu, sGi, deg, acc);
  k_deg<<<(NNZ + 255) / 256, 256, 0, stream>>>(ii, deg);
  k_scan<<<1, 256, 0, stream>>>(deg, rowptr, cursor);
  k_fill<<<(NNZ + 255) / 256, 256, 0, stream>>>(ii, cursor, eids);

  const float* cu = Eu_a; const float* ci = Ei_a;
  float* nu = Eu_b; float* ni = Ei_b;
  for (int l = 0; l < 2; ++l) {
    k_feat<<<(N_TOT + 15) / 16, 256, 0, stream>>>(cu, ci, W, al, ar, feat, el, er);
    k_user_layer<<<(N_U * D) / 256, 256, 0, stream>>>(cu, ci, feat, el, er, vals, ii, nu, sEu, sGu);
    k_item_layer<<<(N_I * D) / 256, 256, 0, stream>>>(cu, ci, feat, el, er, vals, ui, rowptr, eids, ni, sEi, sGi);
    const float* tu = cu; cu = nu; nu = (float*)tu;
    const float* ti = ci; ci = ni; ni = (float*)ti;
  }

  k_cvt_e<<<((PAD_U + PAD_I) * 64) / 256, 256, 0, stream>>>(sEu, sEi, EuH, EuL, EiH, EiL);
  k_cvt_q<<<(2 * B * 64) / 256, 256, 0, stream>>>(sGu, sGi, uids, iids, QuH, QuL, QiH, QiL);
  k_lse_mfma<<<dim3(B / 128, NSP), 256, 0, stream>>>(QuH, QuL, EuH, EuL, N_U, RSP_U, pmU, psU);
  k_lse_mfma<<<dim3(B / 128, NSP), 256, 0, stream>>>(QiH, QiL, EiH, EiL, N_I, RSP_I, pmI, psI);
  k_reg<<<256, 256, 0, stream>>>(Eu0, Ei0, acc);
  k_small<<<B / 256, 256, 0, stream>>>(sEu, sEi, sGu, sGi, uids, iids, pos, neg,
                                       pmU, psU, pmI, psI, acc);
  k_final<<<1, 1, 0, stream>>>(acc, out);
}

// Round 5
// 491.141 us; speedup vs baseline: 12.5738x; 1.5283x over previous
//
#include <hip/hip_runtime.h>
#include <math.h>

#define N_U 30000
#define N_I 15000
#define N_TOT 45000
#define D 64
#define NNZ 480000
#define B 2048
#define INV_TEMP 5.0f
#define LOG_EPS -18.420680743952367f
#define NEG_SLOPE 0.2f
#define LAMBDA1 0.2f
#define LAMBDA2 1e-7f

// MFMA-lse config
#define NSP 64
#define RSP_U 469
#define RSP_I 235
#define PAD_U 30016
#define PAD_I 15040
#define SCALE_LOG2 7.2134752044448170f  // INV_TEMP * log2(e)
#define LN2F 0.6931471805599453f

typedef __attribute__((ext_vector_type(8))) short short8;
typedef __attribute__((ext_vector_type(4))) float f32x4;

__device__ inline float wred(float v) {
#pragma unroll
  for (int o = 32; o > 0; o >>= 1) v += __shfl_down(v, o, 64);
  return v;
}

__device__ inline float leaky(float v) { return (v >= 0.f) ? v : NEG_SLOPE * v; }

// branchless online-softmax accumulate: running (m, denom, o) <- logit l, feature f
__device__ inline void oupd(float& m, float& den, float& o, float l, float f) {
  float delta = l - m;
  float ex = __expf(-fabsf(delta));
  bool gt = delta > 0.f;
  den = gt ? fmaf(den, ex, 1.f) : (den + ex);
  o   = gt ? fmaf(o, ex, f)     : fmaf(ex, f, o);
  m   = gt ? l : m;
}

__device__ inline unsigned short f2bf(float x) {
  unsigned u = __float_as_uint(x);
  unsigned r = u + 0x7FFFu + ((u >> 16) & 1u);
  return (unsigned short)(r >> 16);
}
__device__ inline float bf2f(unsigned short h) {
  return __uint_as_float(((unsigned)h) << 16);
}

// ---------------- init: fused E-part + sums, zero deg/acc ----------------
__global__ void k_init(const float* __restrict__ Eu0, const float* __restrict__ Ei0,
                       float* fU, float* fI, float* sEu, float* sEi,
                       float* sGu, float* sGi, int* deg, float* acc) {
  int t = blockIdx.x * 256 + threadIdx.x;
  if (t < 16) acc[t] = 0.f;
  if (t < N_I) deg[t] = 0;
  if (t < N_U * D) {
    int n = t >> 6, c = t & 63;
    float v = Eu0[t];
    fU[(size_t)n * 128 + c] = v;
    sEu[t] = v; sGu[t] = v;
  } else if (t < N_TOT * D) {
    int j = t - N_U * D;
    int n = j >> 6, c = j & 63;
    float v = Ei0[j];
    fI[(size_t)n * 128 + c] = v;
    sEi[j] = v; sGi[j] = v;
  }
}

// ---------------- CSR build over item side ----------------
__global__ void k_deg(const int* __restrict__ ii, int* deg) {
  int e = blockIdx.x * 256 + threadIdx.x;
  if (e < NNZ) atomicAdd(&deg[ii[e]], 1);
}

__global__ void k_scan(const int* __restrict__ deg, int* rowptr, int* cursor) {
  __shared__ int buf[1024];
  __shared__ int carry;
  int tid = threadIdx.x;
  if (tid == 0) carry = 0;
  __syncthreads();
  for (int base = 0; base < N_I; base += 1024) {
    int v = (base + tid < N_I) ? deg[base + tid] : 0;
    buf[tid] = v;
    __syncthreads();
    for (int o = 1; o < 1024; o <<= 1) {
      int x = (tid >= o) ? buf[tid - o] : 0;
      __syncthreads();
      buf[tid] += x;
      __syncthreads();
    }
    if (base + tid < N_I) {
      int excl = carry + buf[tid] - v;
      rowptr[base + tid] = excl;
      cursor[base + tid] = excl;
    }
    __syncthreads();
    if (tid == 1023) carry += buf[1023];
    __syncthreads();
  }
  if (tid == 0) rowptr[N_I] = carry;
}

// sorted edge arrays: u index (= e>>4 by construction) and val, in CSR position
__global__ void k_fill(const int* __restrict__ ii, const float* __restrict__ vals,
                       int* cursor, int* u_srt, float* v_srt) {
  int e = blockIdx.x * 256 + threadIdx.x;
  if (e < NNZ) {
    int pos = atomicAdd(&cursor[ii[e]], 1);
    u_srt[pos] = e >> 4;
    v_srt[pos] = vals[e];
  }
}

// ---------------- GAT: feat = E @ W into fused[64:128], el/er ----------------
__global__ void k_feat(float* __restrict__ fU, float* __restrict__ fI,
                       const float* __restrict__ W, const float* __restrict__ al,
                       const float* __restrict__ ar,
                       float* __restrict__ el, float* __restrict__ er) {
  __shared__ float Ws[64 * 64];
  __shared__ float hs[16][64];
  int tid = threadIdx.x;
  for (int t = tid; t < 1024; t += 256) ((float4*)Ws)[t] = ((const float4*)W)[t];
  int g = tid >> 6, c = tid & 63;
  int n0 = blockIdx.x * 16 + g * 4;
  float* rows[4];
#pragma unroll
  for (int j = 0; j < 4; j++) {
    int node = n0 + j;
    rows[j] = nullptr;
    if (node < N_TOT) {
      rows[j] = (node < N_U) ? (fU + (size_t)node * 128) : (fI + (size_t)(node - N_U) * 128);
      hs[g * 4 + j][c] = rows[j][c];
    }
  }
  __syncthreads();
  float a0 = 0.f, a1 = 0.f, a2 = 0.f, a3 = 0.f;
#pragma unroll 8
  for (int k = 0; k < 64; ++k) {
    float w = Ws[k * 64 + c];
    a0 = fmaf(hs[g * 4 + 0][k], w, a0);
    a1 = fmaf(hs[g * 4 + 1][k], w, a1);
    a2 = fmaf(hs[g * 4 + 2][k], w, a2);
    a3 = fmaf(hs[g * 4 + 3][k], w, a3);
  }
  float accs[4] = {a0, a1, a2, a3};
  float alc = al[c], arc = ar[c];
#pragma unroll
  for (int j = 0; j < 4; j++) {
    int node = n0 + j;
    if (node >= N_TOT) continue;
    rows[j][64 + c] = accs[j];
    float pl = accs[j] * alc;
    float pr = accs[j] * arc;
#pragma unroll
    for (int o = 8; o >= 1; o >>= 1) {
      pl += __shfl_down(pl, o, 16);
      pr += __shfl_down(pr, o, 16);
    }
    if ((c & 15) == 0) {
      el[node * 4 + (c >> 4)] = pl;
      er[node * 4 + (c >> 4)] = pr;
    }
  }
}

// ---------------- fused user-side layer: single-pass online softmax ----------------
__global__ void k_user_layer(const float* __restrict__ fU_cur, const float* __restrict__ fI_cur,
                             const float* __restrict__ el, const float* __restrict__ er,
                             const float* __restrict__ vals, const int* __restrict__ ii,
                             float* __restrict__ fU_nxt, float* __restrict__ sEu,
                             float* __restrict__ sGu) {
  int t = blockIdx.x * 256 + threadIdx.x;
  int u = t >> 6, c = t & 63;
  if (u >= N_U) return;
  int h = c >> 4;
  float eru = er[u * 4 + h];
  const float* selfrow = fU_cur + (size_t)u * 128;
  float m = leaky(el[u * 4 + h] + eru);
  float den = 1.f;
  float o = selfrow[64 + c];
  float z = 0.f;
  int idx[16]; float vv[16];
#pragma unroll
  for (int k = 0; k < 16; k++) { idx[k] = ii[u * 16 + k]; vv[k] = vals[u * 16 + k]; }
#pragma unroll
  for (int k = 0; k < 16; k++) {
    const float* row = fI_cur + (size_t)idx[k] * 128;
    float e = row[c], f = row[64 + c];
    z = fmaf(vv[k], e, z);
    float l = leaky(el[(idx[k] + N_U) * 4 + h] + eru);
    oupd(m, den, o, l, f);
  }
  o /= den;
  float g = (o > 0.f) ? o : expm1f(o);
  float e_new = selfrow[c] + z;
  fU_nxt[(size_t)u * 128 + c] = e_new;
  size_t off = (size_t)u * D + c;
  sEu[off] += e_new;
  sGu[off] += g;
}

// ---------------- fused item-side layer: CSR, single-pass, unroll-4 ----------------
__global__ void k_item_layer(const float* __restrict__ fU_cur, const float* __restrict__ fI_cur,
                             const float* __restrict__ el, const float* __restrict__ er,
                             const int* __restrict__ rowptr, const int* __restrict__ u_srt,
                             const float* __restrict__ v_srt,
                             float* __restrict__ fI_nxt, float* __restrict__ sEi,
                             float* __restrict__ sGi) {
  int t = blockIdx.x * 256 + threadIdx.x;
  int i = t >> 6, c = t & 63;
  if (i >= N_I) return;
  int h = c >> 4;
  int node = N_U + i;
  float eri = er[node * 4 + h];
  const float* selfrow = fI_cur + (size_t)i * 128;
  float m = leaky(el[node * 4 + h] + eri);
  float den = 1.f;
  float o = selfrow[64 + c];
  float z = 0.f;
  int r0 = rowptr[i], r1 = rowptr[i + 1];
  int r = r0;
  for (; r + 3 < r1; r += 4) {
    int u0 = u_srt[r], u1 = u_srt[r + 1], u2 = u_srt[r + 2], u3 = u_srt[r + 3];
    float v0 = v_srt[r], v1 = v_srt[r + 1], v2 = v_srt[r + 2], v3 = v_srt[r + 3];
    const float* R0 = fU_cur + (size_t)u0 * 128;
    const float* R1 = fU_cur + (size_t)u1 * 128;
    const float* R2 = fU_cur + (size_t)u2 * 128;
    const float* R3 = fU_cur + (size_t)u3 * 128;
    float e0 = R0[c], f0 = R0[64 + c];
    float e1 = R1[c], f1 = R1[64 + c];
    float e2 = R2[c], f2 = R2[64 + c];
    float e3 = R3[c], f3 = R3[64 + c];
    float l0 = leaky(el[u0 * 4 + h] + eri);
    float l1 = leaky(el[u1 * 4 + h] + eri);
    float l2 = leaky(el[u2 * 4 + h] + eri);
    float l3 = leaky(el[u3 * 4 + h] + eri);
    z = fmaf(v0, e0, z); z = fmaf(v1, e1, z); z = fmaf(v2, e2, z); z = fmaf(v3, e3, z);
    oupd(m, den, o, l0, f0);
    oupd(m, den, o, l1, f1);
    oupd(m, den, o, l2, f2);
    oupd(m, den, o, l3, f3);
  }
  for (; r < r1; r++) {
    int u0 = u_srt[r];
    float v0 = v_srt[r];
    const float* R0 = fU_cur + (size_t)u0 * 128;
    float e0 = R0[c], f0 = R0[64 + c];
    float l0 = leaky(el[u0 * 4 + h] + eri);
    z = fmaf(v0, e0, z);
    oupd(m, den, o, l0, f0);
  }
  o /= den;
  float g = (o > 0.f) ? o : expm1f(o);
  float e_new = selfrow[c] + z;
  fI_nxt[(size_t)i * 128 + c] = e_new;
  size_t off = (size_t)i * D + c;
  sEi[off] += e_new;
  sGi[off] += g;
}

// ---------------- split-bf16 conversion: E matrices (zero pad rows) ----------------
__global__ void k_cvt_e(const float* __restrict__ sEu, const float* __restrict__ sEi,
                        unsigned short* __restrict__ EuH, unsigned short* __restrict__ EuL,
                        unsigned short* __restrict__ EiH, unsigned short* __restrict__ EiL) {
  int t = blockIdx.x * 256 + threadIdx.x;
  const int nu = PAD_U * 64;
  const int ntot = (PAD_U + PAD_I) * 64;
  if (t >= ntot) return;
  if (t < nu) {
    int row = t >> 6;
    float x = (row < N_U) ? sEu[t] : 0.f;
    unsigned short hi = f2bf(x);
    EuH[t] = hi;
    EuL[t] = f2bf(x - bf2f(hi));
  } else {
    int t2 = t - nu;
    int row = t2 >> 6;
    float x = (row < N_I) ? sEi[t2] : 0.f;
    unsigned short hi = f2bf(x);
    EiH[t2] = hi;
    EiL[t2] = f2bf(x - bf2f(hi));
  }
}

// ---------------- split-bf16 conversion: gathered query matrices ----------------
__global__ void k_cvt_q(const float* __restrict__ sGu, const float* __restrict__ sGi,
                        const int* __restrict__ uids, const int* __restrict__ iids,
                        unsigned short* __restrict__ QuH, unsigned short* __restrict__ QuL,
                        unsigned short* __restrict__ QiH, unsigned short* __restrict__ QiL) {
  int t = blockIdx.x * 256 + threadIdx.x;
  int side = t >> 17;
  int t2 = t & (B * 64 - 1);
  int b = t2 >> 6, k = t2 & 63;
  int id = side ? iids[b] : uids[b];
  float x = side ? sGi[(size_t)id * 64 + k] : sGu[(size_t)id * 64 + k];
  unsigned short hi = f2bf(x);
  unsigned short lo = f2bf(x - bf2f(hi));
  if (side) { QiH[t2] = hi; QiL[t2] = lo; }
  else      { QuH[t2] = hi; QuL[t2] = lo; }
}

// ---------------- MFMA logsumexp ----------------
__global__ __launch_bounds__(256) void k_lse_mfma(
    const unsigned short* __restrict__ Qhi, const unsigned short* __restrict__ Qlo,
    const unsigned short* __restrict__ Ehi, const unsigned short* __restrict__ Elo,
    int n_rows, int rows_per_split,
    float* __restrict__ part_m, float* __restrict__ part_s) {
  int tid = threadIdx.x;
  int wave = tid >> 6, lane = tid & 63;
  int l15 = lane & 15, quad = lane >> 4;
  int qt0 = blockIdx.x * 128 + wave * 32;
  int split = blockIdx.y;
  int row0 = split * rows_per_split;
  int row_end = min(row0 + rows_per_split, n_rows);

  short8 ah[2][2], al[2][2];
#pragma unroll
  for (int t = 0; t < 2; t++)
#pragma unroll
    for (int c = 0; c < 2; c++) {
      size_t idx = (size_t)(qt0 + t * 16 + l15) * 64 + c * 32 + quad * 8;
      ah[t][c] = *(const short8*)(Qhi + idx);
      al[t][c] = *(const short8*)(Qlo + idx);
    }

  float mst[2][4], sst[2][4];
#pragma unroll
  for (int t = 0; t < 2; t++)
#pragma unroll
    for (int g = 0; g < 4; g++) { mst[t][g] = -1e30f; sst[t][g] = 0.f; }

  for (int rb = row0; rb < row_end; rb += 16) {
    int r = rb + l15;
    bool valid = r < row_end;
    size_t eb = (size_t)r * 64 + quad * 8;
    short8 bh0 = *(const short8*)(Ehi + eb);
    short8 bh1 = *(const short8*)(Ehi + eb + 32);
    short8 bl0 = *(const short8*)(Elo + eb);
    short8 bl1 = *(const short8*)(Elo + eb + 32);

#pragma unroll
    for (int t = 0; t < 2; t++) {
      f32x4 acc = {0.f, 0.f, 0.f, 0.f};
      acc = __builtin_amdgcn_mfma_f32_16x16x32_bf16(ah[t][0], bh0, acc, 0, 0, 0);
      acc = __builtin_amdgcn_mfma_f32_16x16x32_bf16(ah[t][1], bh1, acc, 0, 0, 0);
      acc = __builtin_amdgcn_mfma_f32_16x16x32_bf16(al[t][0], bh0, acc, 0, 0, 0);
      acc = __builtin_amdgcn_mfma_f32_16x16x32_bf16(al[t][1], bh1, acc, 0, 0, 0);
      acc = __builtin_amdgcn_mfma_f32_16x16x32_bf16(ah[t][0], bl0, acc, 0, 0, 0);
      acc = __builtin_amdgcn_mfma_f32_16x16x32_bf16(ah[t][1], bl1, acc, 0, 0, 0);
#pragma unroll
      for (int g = 0; g < 4; g++) {
        float d = valid ? acc[g] * SCALE_LOG2 : -2e30f;
        float mo = mst[t][g];
        float delta = d - mo;
        float e = exp2f(-fabsf(delta));
        bool gt = delta > 0.f;
        sst[t][g] = gt ? (sst[t][g] * e + 1.f) : (sst[t][g] + e);
        mst[t][g] = gt ? d : mo;
      }
    }
  }

#pragma unroll
  for (int off = 1; off < 16; off <<= 1) {
#pragma unroll
    for (int t = 0; t < 2; t++)
#pragma unroll
      for (int g = 0; g < 4; g++) {
        float om = __shfl_xor(mst[t][g], off, 64);
        float os = __shfl_xor(sst[t][g], off, 64);
        float mn = fmaxf(mst[t][g], om);
        sst[t][g] = sst[t][g] * exp2f(mst[t][g] - mn) + os * exp2f(om - mn);
        mst[t][g] = mn;
      }
  }
  if (l15 == 0) {
#pragma unroll
    for (int t = 0; t < 2; t++)
#pragma unroll
      for (int g = 0; g < 4; g++) {
        int q = qt0 + t * 16 + quad * 4 + g;
        part_m[(size_t)q * NSP + split] = mst[t][g];
        part_s[(size_t)q * NSP + split] = sst[t][g];
      }
  }
}

// ---------------- L2 regularization reduce ----------------
__global__ void k_reg(const float* __restrict__ Eu0, const float* __restrict__ Ei0, float* acc) {
  __shared__ float red[4];
  int tid = threadIdx.x;
  float s = 0.f;
  const float4* A = (const float4*)Eu0;
  const float4* Bp = (const float4*)Ei0;
  const int nA = N_U * 16, nTot = N_TOT * 16;
  for (int t = blockIdx.x * 256 + tid; t < nTot; t += 256 * 256) {
    float4 v = (t < nA) ? A[t] : Bp[t - nA];
    s += v.x * v.x + v.y * v.y + v.z * v.z + v.w * v.w;
  }
  s = wred(s);
  if ((tid & 63) == 0) red[tid >> 6] = s;
  __syncthreads();
  if (tid == 0) unsafeAtomicAdd(acc + 5, red[0] + red[1] + red[2] + red[3]);
}

// ---------------- per-sample losses ----------------
__global__ void k_small(const float* __restrict__ sEu, const float* __restrict__ sEi,
                        const float* __restrict__ sGu, const float* __restrict__ sGi,
                        const int* __restrict__ uids, const int* __restrict__ iids,
                        const int* __restrict__ pos, const int* __restrict__ neg,
                        const float* __restrict__ pmU, const float* __restrict__ psU,
                        const float* __restrict__ pmI, const float* __restrict__ psI,
                        float* acc) {
  int b = blockIdx.x * 256 + threadIdx.x;
  float du = 0.f, di = 0.f, nu = 0.f, ni = 0.f, bpr = 0.f;
  if (b < B) {
    float mm = -1e30f, ss = 0.f;
    for (int s2 = 0; s2 < NSP; s2++) {
      float mj = pmU[(size_t)b * NSP + s2];
      float sj = psU[(size_t)b * NSP + s2];
      float mn = fmaxf(mm, mj);
      ss = ss * exp2f(mm - mn) + sj * exp2f(mj - mn);
      mm = mn;
    }
    float lseu = mm * LN2F + logf(ss);
    mm = -1e30f; ss = 0.f;
    for (int s2 = 0; s2 < NSP; s2++) {
      float mj = pmI[(size_t)b * NSP + s2];
      float sj = psI[(size_t)b * NSP + s2];
      float mn = fmaxf(mm, mj);
      ss = ss * exp2f(mm - mn) + sj * exp2f(mj - mn);
      mm = mn;
    }
    float lsei = mm * LN2F + logf(ss);
    nu = fmaxf(lseu, LOG_EPS) + log1pf(expf(-fabsf(lseu - LOG_EPS)));
    ni = fmaxf(lsei, LOG_EPS) + log1pf(expf(-fabsf(lsei - LOG_EPS)));

    int u = uids[b], it = iids[b], p = pos[b], ng = neg[b];
    const float4* gu = (const float4*)(sGu + (size_t)u * D);
    const float4* eu = (const float4*)(sEu + (size_t)u * D);
    const float4* gi = (const float4*)(sGi + (size_t)it * D);
    const float4* ei = (const float4*)(sEi + (size_t)it * D);
    const float4* ep = (const float4*)(sEi + (size_t)p * D);
    const float4* en = (const float4*)(sEi + (size_t)ng * D);
    float diff = 0.f;
#pragma unroll
    for (int k = 0; k < 16; k++) {
      float4 a = gu[k], b4 = eu[k];
      du += a.x * b4.x + a.y * b4.y + a.z * b4.z + a.w * b4.w;
      float4 c = gi[k], d4 = ei[k];
      di += c.x * d4.x + c.y * d4.y + c.z * d4.z + c.w * d4.w;
      float4 e = ep[k], f = en[k];
      diff += b4.x * (e.x - f.x) + b4.y * (e.y - f.y) + b4.z * (e.z - f.z) + b4.w * (e.w - f.w);
    }
    bpr = (diff > 0.f) ? log1pf(expf(-diff)) : (-diff + log1pf(expf(diff)));
  }
  du = wred(du); di = wred(di); nu = wred(nu); ni = wred(ni); bpr = wred(bpr);
  if ((threadIdx.x & 63) == 0) {
    unsafeAtomicAdd(acc + 0, du);
    unsafeAtomicAdd(acc + 1, di);
    unsafeAtomicAdd(acc + 2, nu);
    unsafeAtomicAdd(acc + 3, ni);
    unsafeAtomicAdd(acc + 4, bpr);
  }
}

// ---------------- finalize ----------------
__global__ void k_final(const float* __restrict__ acc, float* __restrict__ out) {
  float pos_score = (acc[0] + acc[1]) * (INV_TEMP / (float)B);
  float neg_score = (acc[2] + acc[3]) / (float)B;
  float loss_s = neg_score - pos_score;
  float loss_r = acc[4] / (float)B;
  float reg = LAMBDA2 * acc[5];
  out[0] = loss_r + LAMBDA1 * loss_s + reg;
  out[1] = loss_r;
  out[2] = LAMBDA1 * loss_s;
}

extern "C" void kernel_launch(void* const* d_in, const int* in_sizes, int n_in,
                              void* d_out, int out_size, void* d_ws, size_t ws_size,
                              hipStream_t stream) {
  const float* Eu0  = (const float*)d_in[0];
  const float* Ei0  = (const float*)d_in[1];
  const float* vals = (const float*)d_in[2];
  const float* W    = (const float*)d_in[3];
  const float* al   = (const float*)d_in[4];
  const float* ar   = (const float*)d_in[5];
  const int* ii     = (const int*)d_in[7];
  const int* uids   = (const int*)d_in[10];
  const int* iids   = (const int*)d_in[11];
  const int* pos    = (const int*)d_in[12];
  const int* neg    = (const int*)d_in[13];
  float* out = (float*)d_out;

  char* base = (char*)d_ws;
  size_t off = 0;
  auto alloc = [&](size_t bytes) -> void* {
    void* p = base + off;
    off = (off + bytes + 255) & ~(size_t)255;
    return p;
  };
  float* fU_a = (float*)alloc((size_t)N_U * 128 * 4);
  float* fU_b = (float*)alloc((size_t)N_U * 128 * 4);
  float* fI_a = (float*)alloc((size_t)N_I * 128 * 4);
  float* fI_b = (float*)alloc((size_t)N_I * 128 * 4);
  float* sEu  = (float*)alloc((size_t)N_U * D * 4);
  float* sEi  = (float*)alloc((size_t)N_I * D * 4);
  float* sGu  = (float*)alloc((size_t)N_U * D * 4);
  float* sGi  = (float*)alloc((size_t)N_I * D * 4);
  float* el   = (float*)alloc((size_t)N_TOT * 4 * 4);
  float* er   = (float*)alloc((size_t)N_TOT * 4 * 4);
  float* pmU  = (float*)alloc((size_t)B * NSP * 4);
  float* psU  = (float*)alloc((size_t)B * NSP * 4);
  float* pmI  = (float*)alloc((size_t)B * NSP * 4);
  float* psI  = (float*)alloc((size_t)B * NSP * 4);
  float* acc  = (float*)alloc(16 * 4);
  int* deg    = (int*)alloc((size_t)N_I * 4);
  int* cursor = (int*)alloc((size_t)N_I * 4);
  int* rowptr = (int*)alloc((size_t)(N_I + 1) * 4);
  int* u_srt  = (int*)alloc((size_t)NNZ * 4);
  float* v_srt= (float*)alloc((size_t)NNZ * 4);
  unsigned short* EuH = (unsigned short*)alloc((size_t)PAD_U * 64 * 2);
  unsigned short* EuL = (unsigned short*)alloc((size_t)PAD_U * 64 * 2);
  unsigned short* EiH = (unsigned short*)alloc((size_t)PAD_I * 64 * 2);
  unsigned short* EiL = (unsigned short*)alloc((size_t)PAD_I * 64 * 2);
  unsigned short* QuH = (unsigned short*)alloc((size_t)B * 64 * 2);
  unsigned short* QuL = (unsigned short*)alloc((size_t)B * 64 * 2);
  unsigned short* QiH = (unsigned short*)alloc((size_t)B * 64 * 2);
  unsigned short* QiL = (unsigned short*)alloc((size_t)B * 64 * 2);

  k_init<<<(N_TOT * D + 255) / 256, 256, 0, stream>>>(Eu0, Ei0, fU_a, fI_a, sEu, sEi, sGu, sGi, deg, acc);
  k_deg<<<(NNZ + 255) / 256, 256, 0, stream>>>(ii, deg);
  k_scan<<<1, 1024, 0, stream>>>(deg, rowptr, cursor);
  k_fill<<<(NNZ + 255) / 256, 256, 0, stream>>>(ii, vals, cursor, u_srt, v_srt);

  float* cu = fU_a; float* ci = fI_a;
  float* nu = fU_b; float* ni = fI_b;
  for (int l = 0; l < 2; ++l) {
    k_feat<<<(N_TOT + 15) / 16, 256, 0, stream>>>(cu, ci, W, al, ar, el, er);
    k_user_layer<<<(N_U * D) / 256, 256, 0, stream>>>(cu, ci, el, er, vals, ii, nu, sEu, sGu);
    k_item_layer<<<(N_I * D) / 256, 256, 0, stream>>>(cu, ci, el, er, rowptr, u_srt, v_srt, ni, sEi, sGi);
    float* t1 = cu; cu = nu; nu = t1;
    float* t2 = ci; ci = ni; ni = t2;
  }

  k_cvt_e<<<((PAD_U + PAD_I) * 64) / 256, 256, 0, stream>>>(sEu, sEi, EuH, EuL, EiH, EiL);
  k_cvt_q<<<(2 * B * 64) / 256, 256, 0, stream>>>(sGu, sGi, uids, iids, QuH, QuL, QiH, QiL);
  k_lse_mfma<<<dim3(B / 128, NSP), 256, 0, stream>>>(QuH, QuL, EuH, EuL, N_U, RSP_U, pmU, psU);
  k_lse_mfma<<<dim3(B / 128, NSP), 256, 0, stream>>>(QiH, QiL, EiH, EiL, N_I, RSP_I, pmI, psI);
  k_reg<<<256, 256, 0, stream>>>(Eu0, Ei0, acc);
  k_small<<<B / 256, 256, 0, stream>>>(sEu, sEi, sGu, sGi, uids, iids, pos, neg,
                                       pmU, psU, pmI, psI, acc);
  k_final<<<1, 1, 0, stream>>>(acc, out);
}